// Round 2
// baseline (917.037 us; speedup 1.0000x reference)
//
#include <hip/hip_runtime.h>
#include <hip/hip_bf16.h>

#define HH 192
#define WW 192
#define HW (HH*WW)

typedef unsigned short u16;
typedef __attribute__((ext_vector_type(8))) short short8;
typedef __attribute__((ext_vector_type(16))) float float16;

__device__ __forceinline__ float b2f(u16 u){
  union { unsigned int i; float f; } v; v.i = ((unsigned int)u) << 16; return v.f;
}
__device__ __forceinline__ u16 f2b(float f){
  union { unsigned int i; float f; } v; v.f = f;
  unsigned int r = v.i + 0x7FFFu + ((v.i >> 16) & 1u);
  return (u16)(r >> 16);
}
__device__ __forceinline__ void up2(unsigned int w, float& lo, float& hi){
  union { unsigned int i; float f; } a, b;
  a.i = w << 16; b.i = w & 0xFFFF0000u;
  lo = a.f; hi = b.f;
}
__device__ __forceinline__ float lrelu(float x){ return x >= 0.f ? x : 0.1f*x; }
__device__ __forceinline__ float ldmix(const void* p, int i, bool bf){
  return bf ? b2f(((const u16*)p)[i]) : ((const float*)p)[i];
}

using bf2 = __attribute__((ext_vector_type(2))) __bf16;
__device__ __forceinline__ float dot2bf(unsigned int a, unsigned int b, float c){
#if __has_builtin(__builtin_amdgcn_fdot2_f32_bf16)
  union { unsigned int u; bf2 v; } ua, ub; ua.u = a; ub.u = b;
  return __builtin_amdgcn_fdot2_f32_bf16(ua.v, ub.v, c, false);
#else
  float al,ah,bl,bh; up2(a,al,ah); up2(b,bl,bh);
  return c + al*bl + ah*bh;
#endif
}

__global__ __launch_bounds__(256) void detect_k(const unsigned int* __restrict__ w, int* __restrict__ flag){
  __shared__ int cnt;
  if (threadIdx.x == 0) cnt = 0;
  __syncthreads();
  unsigned int v = w[(size_t)threadIdx.x * 1024];
  int e = (v >> 7) & 0xFF;
  bool ok = ((v & 0xFFFFu) == 0u) || (e > 100 && e < 150);
  if (ok) atomicAdd(&cnt, 1);
  __syncthreads();
  if (threadIdx.x == 0) *flag = (cnt >= 192) ? 1 : 0;
}

// NCHW (fp32 or bf16) -> NHWC bf16 [8][HW][64] via LDS transpose tile.
__global__ __launch_bounds__(256) void cvt_t(const void* __restrict__ pred, const void* __restrict__ refp,
                                             u16* __restrict__ X1, const int* __restrict__ flag){
  __shared__ u16 t[64*72];
  int tid = threadIdx.x;
  int px0 = blockIdx.x*64, img = blockIdx.y;
  bool bf = (*flag != 0);
  const void* src = (img < 4) ? pred : refp;
  int im = (img < 4) ? img : img - 4;
  for (int e = tid; e < 4096; e += 256){
    int ch = e >> 6, px = e & 63;
    t[px*72 + ch] = f2b(ldmix(src, (im*64 + ch)*HW + px0 + px, bf));
  }
  __syncthreads();
  int px = tid >> 2, q = tid & 3;
  uint4 v0 = *(const uint4*)(t + px*72 + q*16);
  uint4 v1 = *(const uint4*)(t + px*72 + q*16 + 8);
  u16* dst = X1 + ((size_t)img*HW + px0 + px)*64 + q*16;
  *(uint4*)dst = v0;
  *(uint4*)(dst + 8) = v1;
}

// Weight prep:
//  w1m/w2m: bf16 in MFMA A-frag lane order: [tap][ks][cotile][lane][8],
//           elem = W[co=cot*32+(lane&31)][ci=ks*16+(lane>>5)*8+j][tap]
//  wrf: fp32 [ci][co] (redir); wpb: packed bf16 pairs (final); biases fp32.
__global__ __launch_bounds__(256) void prep_w(const void* __restrict__ w1, const void* __restrict__ w2,
                                              const void* __restrict__ wr, const void* __restrict__ wp,
                                              const void* __restrict__ b1, const void* __restrict__ b2,
                                              const void* __restrict__ rb,
                                              u16* __restrict__ w1m, u16* __restrict__ w2m,
                                              float* __restrict__ wrf, unsigned int* __restrict__ wpb,
                                              float* __restrict__ b1f, float* __restrict__ b2f,
                                              float* __restrict__ rbf, const int* __restrict__ flag){
  int i = blockIdx.x*256 + threadIdx.x;
  bool bf = (*flag != 0);
  if (i < 36864){
    int j = i & 7, lane = (i>>3) & 63, cot = (i>>9) & 1, ks = (i>>10) & 3, tap = i >> 12;
    int co = cot*32 + (lane & 31), ci = ks*16 + (lane>>5)*8 + j;
    w1m[i] = f2b(ldmix(w1, (co*64 + ci)*9 + tap, bf));
  }
  if (i < 73728){
    int j = i & 7, lane = (i>>3) & 63, cot = (i>>9) & 3, ks = (i>>11) & 3, tap = i >> 13;
    int co = cot*32 + (lane & 31), ci = ks*16 + (lane>>5)*8 + j;
    w2m[i] = f2b(ldmix(w2, (co*64 + ci)*9 + tap, bf));
  }
  if (i < 4096){ int co = i & 31; int ci = i >> 5;
    wrf[ci*32+co] = ldmix(wr, co*128+ci, bf); }
  if (i < 4266){
    int cp = i/18; int rr = i - cp*18; int tap = rr >> 1; int o = rr & 1;
    int c0 = 2*cp, c1 = c0 + 1;
    float f0 = ldmix(wp, (o*473+c0)*9+tap, bf);
    float f1 = (c1 < 473) ? ldmix(wp, (o*473+c1)*9+tap, bf) : 0.f;
    wpb[i] = (unsigned int)f2b(f0) | ((unsigned int)f2b(f1) << 16);
  }
  if (i < 64)  b1f[i] = ldmix(b1, i, bf);
  if (i < 128) b2f[i] = ldmix(b2, i, bf);
  if (i < 32)  rbf[i] = ldmix(rb, i, bf);
}

// MFMA implicit-GEMM 3x3 conv, pad=1, NHWC bf16 in/out, bias+lrelu.
template<int WCO>
__global__ __launch_bounds__(WCO*128) void conv_mfma(const u16* __restrict__ in, const u16* __restrict__ wm,
                                                     const float* __restrict__ bias, u16* __restrict__ out){
  constexpr int COUT = WCO*64;
  constexpr int NCOT = WCO*2;
  constexpr int THREADS = WCO*128;
  constexpr int CO_PAD = COUT + 8;
  constexpr int SLAB = 6*34*72;            // 14688 u16
  constexpr int OT   = 128*CO_PAD;
  __shared__ __align__(16) u16 smem[(SLAB > OT) ? SLAB : OT];

  int tid = threadIdx.x, lane = tid & 63, w = tid >> 6;
  int wr = w & 1, wc = w >> 1;
  int n = lane & 31, kh = lane >> 5;
  int x0 = blockIdx.x*32, y0 = blockIdx.y*4, img = blockIdx.z;
  const u16* inb = in + (size_t)img*HW*64;

  float16 acc[2][2];
  #pragma unroll
  for (int t=0;t<2;t++)
    #pragma unroll
    for (int c=0;c<2;c++)
      #pragma unroll
      for (int k=0;k<16;k++) acc[t][c][k] = 0.f;

  for (int e = tid; e < 1632; e += THREADS){
    int c8 = e & 7; int pp = e >> 3;
    int row = pp / 34, pos = pp - row*34;
    int gy = y0 + row - 1, gx = x0 + pos - 1;
    uint4 v = make_uint4(0,0,0,0);
    if (gy >= 0 && gy < HH && gx >= 0 && gx < WW)
      v = *(const uint4*)(inb + ((size_t)gy*WW + gx)*64 + c8*8);
    *(uint4*)(smem + pp*72 + c8*8) = v;
  }
  __syncthreads();

  union AU { uint4 q; short8 s; };
  union BU { uint2 u[2]; short8 s; };

  #pragma unroll 1
  for (int ky = 0; ky < 3; ++ky){
    #pragma unroll 1
    for (int kx = 0; kx < 3; ++kx){
      int tap = ky*3 + kx;
      #pragma unroll
      for (int ks = 0; ks < 4; ++ks){
        AU a0, a1;
        const u16* wmp = wm + (((size_t)(tap*4 + ks)*NCOT + wc*2)*64 + lane)*8;
        a0.q = *(const uint4*)(wmp);
        a1.q = *(const uint4*)(wmp + 512);
        #pragma unroll
        for (int t = 0; t < 2; ++t){
          int row = wr*2 + t + ky;
          int off = (row*34 + n + kx)*72 + ks*16 + kh*8;
          BU b;
          b.u[0] = *(const uint2*)(smem + off);
          b.u[1] = *(const uint2*)(smem + off + 4);
          acc[t][0] = __builtin_amdgcn_mfma_f32_32x32x16_bf16(a0.s, b.s, acc[t][0], 0, 0, 0);
          acc[t][1] = __builtin_amdgcn_mfma_f32_32x32x16_bf16(a1.s, b.s, acc[t][1], 0, 0, 0);
        }
      }
    }
  }

  __syncthreads();
  #pragma unroll
  for (int t = 0; t < 2; ++t){
    int pxl = (wr*2 + t)*32 + n;
    #pragma unroll
    for (int c = 0; c < 2; ++c){
      int cob = wc*64 + c*32 + 4*kh;
      #pragma unroll
      for (int p = 0; p < 8; ++p){
        int co = cob + (p&1)*2 + (p>>1)*8;
        float2 bb = *(const float2*)(bias + co);
        float v0 = lrelu(acc[t][c][2*p]   + bb.x);
        float v1 = lrelu(acc[t][c][2*p+1] + bb.y);
        unsigned int pk = (unsigned int)f2b(v0) | ((unsigned int)f2b(v1) << 16);
        *(unsigned int*)(smem + pxl*CO_PAD + co) = pk;
      }
    }
  }
  __syncthreads();
  int px, part;
  if (WCO == 2){ px = tid >> 1; part = tid & 1; } else { px = tid; part = 0; }
  const u16* sp = smem + px*CO_PAD + part*64;
  u16* gp = out + ((size_t)img*HW + (size_t)(y0 + (px>>5))*WW + x0 + (px&31))*COUT + part*64;
  #pragma unroll
  for (int k = 0; k < 8; ++k)
    *(uint4*)(gp + k*8) = *(const uint4*)(sp + k*8);
}

// 1x1 redir conv (128->32) + bias + lrelu. X NCHW [b][473][HW]; planes 0..31.
__global__ __launch_bounds__(256) void redir_k(const u16* __restrict__ C2, const float* __restrict__ wrf,
                                               const float* __restrict__ rbf, u16* __restrict__ X){
  int p = blockIdx.x*256 + threadIdx.x;
  int b = p / HW; int pix = p - b*HW;
  const u16* ap = C2 + (size_t)p*128;
  float acc[32];
  #pragma unroll
  for (int j=0;j<32;j++) acc[j]=0.f;
  for (int ci=0; ci<128; ci+=4){
    uint2 aw = *(const uint2*)(ap + ci);
    float a0,a1,a2,a3;
    up2(aw.x,a0,a1); up2(aw.y,a2,a3);
    const float* w0 = wrf + ci*32;
    #pragma unroll
    for (int co=0; co<32; co+=4){
      float4 wv0 = *(const float4*)(w0+co);
      float4 wv1 = *(const float4*)(w0+32+co);
      float4 wv2 = *(const float4*)(w0+64+co);
      float4 wv3 = *(const float4*)(w0+96+co);
      acc[co+0] += a0*wv0.x + a1*wv1.x + a2*wv2.x + a3*wv3.x;
      acc[co+1] += a0*wv0.y + a1*wv1.y + a2*wv2.y + a3*wv3.y;
      acc[co+2] += a0*wv0.z + a1*wv1.z + a2*wv2.z + a3*wv3.z;
      acc[co+3] += a0*wv0.w + a1*wv1.w + a2*wv2.w + a3*wv3.w;
    }
  }
  #pragma unroll
  for (int co=0; co<32; ++co){
    X[(size_t)(b*473 + co)*HW + pix] = f2b(lrelu(acc[co] + rbf[co]));
  }
}

// Correlation, round 8.
// Block = 128 threads (2 waves) per (b,y,dy). Each thread owns 3 same-parity
// pixels {x0,x0+2,x0+4} (x0=6g+p). Wave w covers dx in [11w, 11w+10].
// LDS staging is 8-channel chunks, parity-split [parity][116 m][8ch]:
// a thread's windows for 3px x 11dx collapse to 13 contiguous m-reads/chunk.
// Register budget (spill-proof): 33 acc + 12 av + ~4 inflight b + addr < 128.
// Epilogue stages [21][192] u16 in LDS, then writes contiguous dwords
// (full-cacheline coverage -> no partial-line RMW).
// Grid: XCD-bijective swizzle (16128 = 8*2016), dy-fastest for L2 locality.
__device__ __forceinline__ float dot4(const uint4& a, const uint4& b, float c){
  c = dot2bf(a.x, b.x, c);
  c = dot2bf(a.y, b.y, c);
  c = dot2bf(a.z, b.z, c);
  c = dot2bf(a.w, b.w, c);
  return c;
}

__global__ __launch_bounds__(128,4) void corr_k(const u16* __restrict__ C2, u16* __restrict__ X){
  // stage view: [2 parity][116 m][8 u16] = 3712 B; out view: [21][192] u16 = 8064 B
  __shared__ __align__(16) u16 sm[4096];
  int bid = blockIdx.x;
  int v  = (bid & 7) * 2016 + (bid >> 3);         // XCD-contiguous, bijective
  int t21 = v / 21;
  int dy  = v - t21*21;
  int b   = t21 / 192;
  int y   = t21 - b*192;

  int tid = threadIdx.x;
  int lane = tid & 63, w = tid >> 6;
  int p = lane & 1, g = lane >> 1;
  int x0 = 6*g + p;
  int mbase = 11*w;
  int r = y + 2*dy - 20;
  u16* bp0 = X + ((size_t)(b*473 + 32 + dy*21)*HH + y)*WW;

  if (r < 0 || r >= HH){
    #pragma unroll
    for (int i = 0; i < 16; ++i){
      int idx = i*128 + tid;
      if (idx < 2016){
        int dx = idx/96, xw = idx - dx*96;
        *(unsigned int*)(bp0 + (size_t)dx*HW + 2*xw) = 0u;
      }
    }
    return;
  }

  const u16* ap   = C2 + ((size_t)b*HW + (size_t)y*WW + x0)*128;
  const u16* brow = C2 + ((size_t)(b+4)*HW + (size_t)r*WW)*128;

  float acc[3][11];
  #pragma unroll
  for (int t=0;t<3;t++)
    #pragma unroll
    for (int j=0;j<11;j++) acc[t][j]=0.f;

  #pragma unroll 1
  for (int c0 = 0; c0 < 128; c0 += 8){
    if (c0) __syncthreads();
    {
      int e = tid;
      int ep = e & 1, m = e >> 1;
      int gx = 2*m + ep - 20;
      uint4 vv = make_uint4(0,0,0,0);
      if (gx >= 0 && gx < WW) vv = *(const uint4*)(brow + (size_t)gx*128 + c0);
      *(uint4*)(sm + (ep*116 + m)*8) = vv;
      e = tid + 128;
      if (e < 232){
        int ep2 = e & 1, m2 = e >> 1;
        int gx2 = 2*m2 + ep2 - 20;
        uint4 v2 = make_uint4(0,0,0,0);
        if (gx2 >= 0 && gx2 < WW) v2 = *(const uint4*)(brow + (size_t)gx2*128 + c0);
        *(uint4*)(sm + (ep2*116 + m2)*8) = v2;
      }
    }
    __syncthreads();
    uint4 av0 = *(const uint4*)(ap + c0);
    uint4 av1 = *(const uint4*)(ap + 256 + c0);
    uint4 av2 = *(const uint4*)(ap + 512 + c0);
    #pragma unroll
    for (int k = 0; k < 13; ++k){
      int mm = 3*g + mbase + k; mm = min(mm, 115);
      uint4 bb = *(const uint4*)(sm + (p*116 + mm)*8);
      if (k <= 10)            acc[0][k]   = dot4(av0, bb, acc[0][k]);
      if (k >= 1 && k <= 11)  acc[1][k-1] = dot4(av1, bb, acc[1][k-1]);
      if (k >= 2)             acc[2][k-2] = dot4(av2, bb, acc[2][k-2]);
    }
  }

  // epilogue: stage [21][192] in LDS, then contiguous dword stores
  __syncthreads();
  #pragma unroll
  for (int j = 0; j <= 10; ++j){
    if (w == 0 || j < 10){
      int dx = mbase + j;
      u16* row = sm + dx*192;
      row[x0]     = f2b(lrelu(acc[0][j]*(1.f/128.f)));
      row[x0 + 2] = f2b(lrelu(acc[1][j]*(1.f/128.f)));
      row[x0 + 4] = f2b(lrelu(acc[2][j]*(1.f/128.f)));
    }
  }
  __syncthreads();
  #pragma unroll
  for (int i = 0; i < 16; ++i){
    int idx = i*128 + tid;
    if (idx < 2016){
      int dx = idx/96, xw = idx - dx*96;
      *(unsigned int*)(bp0 + (size_t)dx*HW + 2*xw) = *(const unsigned int*)(sm + 2*idx);
    }
  }
}

// Final 3x3 conv: contribution-passing (see round 6).
__global__ __launch_bounds__(192) void final_k(const u16* __restrict__ X, const unsigned int* __restrict__ wpb,
                                               void* __restrict__ out, const int* __restrict__ flag){
  __shared__ float eR[4][2], eL[4][2];
  int x = threadIdx.x, y = blockIdx.x, b = blockIdx.y;
  int w = x >> 6, lane = x & 63;
  const u16* Xb = X + (size_t)b*473*HW;
  float Pm0=0.f,Pm1=0.f,Pl0=0.f,Pl1=0.f,Pr0=0.f,Pr1=0.f;
  bool rok0 = (y > 0), rok2 = (y < HH-1);
  size_t off0 = (size_t)(y-1)*WW + x;
  size_t off1 = (size_t)(y  )*WW + x;
  size_t off2 = (size_t)(y+1)*WW + x;

  for (int cp = 0; cp < 237; ++cp){
    const unsigned int* w18 = wpb + cp*18;
    size_t base0 = (size_t)(2*cp)*HW;
    size_t base1 = base0 + HW;
    bool c1ok = (2*cp+1) < 473;
    #pragma unroll
    for (int r = 0; r < 3; ++r){
      bool ok = (r==0) ? rok0 : ((r==2) ? rok2 : true);
      size_t off = (r==0) ? off0 : ((r==2) ? off2 : off1);
      unsigned int v = 0;
      if (ok){
        unsigned int lo = Xb[base0 + off];
        unsigned int hi = c1ok ? (unsigned int)Xb[base1 + off] : 0u;
        v = lo | (hi << 16);
      }
      Pm0 = dot2bf(v, w18[(r*3+1)*2+0], Pm0);
      Pm1 = dot2bf(v, w18[(r*3+1)*2+1], Pm1);
      Pl0 = dot2bf(v, w18[(r*3+2)*2+0], Pl0);
      Pl1 = dot2bf(v, w18[(r*3+2)*2+1], Pl1);
      Pr0 = dot2bf(v, w18[(r*3+0)*2+0], Pr0);
      Pr1 = dot2bf(v, w18[(r*3+0)*2+1], Pr1);
    }
  }

  float r0 = __shfl_up(Pr0,1), r1 = __shfl_up(Pr1,1);
  float l0 = __shfl_down(Pl0,1), l1 = __shfl_down(Pl1,1);
  if (x == 0){ eR[0][0]=0.f; eR[0][1]=0.f; eL[3][0]=0.f; eL[3][1]=0.f; }
  if (lane == 63){ eR[w+1][0]=Pr0; eR[w+1][1]=Pr1; }
  if (lane == 0 && w > 0){ eL[w][0]=Pl0; eL[w][1]=Pl1; }
  __syncthreads();
  if (lane == 0){ r0 = eR[w][0]; r1 = eR[w][1]; }
  if (lane == 63){ l0 = eL[w+1][0]; l1 = eL[w+1][1]; }
  float a0 = Pm0 + r0 + l0;
  float a1 = Pm1 + r1 + l1;

  size_t rem = (size_t)y*WW + x;
  size_t i0 = (size_t)(b*2)*HW + rem;
  size_t i1 = (size_t)(b*2+1)*HW + rem;
  if (*flag){
    ((u16*)out)[i0] = f2b(a0);
    ((u16*)out)[i1] = f2b(a1);
  } else {
    ((float*)out)[i0] = a0;
    ((float*)out)[i1] = a1;
  }
}

// Workspace (bytes):
//   C2 [0, 75497472)           conv2 out NHWC bf16 [8][HW][128]
//   X1 [75497472, 113246208)   cvt out NHWC bf16 [8][HW][64] (dies after conv1)
//   H1 [113246208, 150994944)  conv1 out NHWC bf16 (dies after conv2)
//   X  [75497472, 214958080)   concat NCHW bf16 [4][473][HW] (overlays X1+H1)
//   weights at 215322624 (~260 KB)
extern "C" void kernel_launch(void* const* d_in, const int* in_sizes, int n_in,
                              void* d_out, int out_size, void* d_ws, size_t ws_size,
                              hipStream_t stream){
  char* ws = (char*)d_ws;
  u16* C2 = (u16*)ws;
  u16* X1 = (u16*)(ws + 75497472);
  u16* H1 = (u16*)(ws + 113246208);
  u16* X  = (u16*)(ws + 75497472);
  u16* w1m = (u16*)(ws + 215322624);
  u16* w2m = w1m + 36864;
  float* wrf = (float*)(w2m + 73728);
  unsigned int* wpb = (unsigned int*)(wrf + 4096);
  float* b1f = (float*)(wpb + 4266);
  float* b2f = b1f + 64;
  float* rbf = b2f + 128;
  int* flag  = (int*)(rbf + 32);

  detect_k<<<1,256,0,stream>>>((const unsigned int*)d_in[0], flag);
  cvt_t<<<dim3(576,8),256,0,stream>>>(d_in[0], d_in[1], X1, flag);
  prep_w<<<288,256,0,stream>>>(d_in[2], d_in[4], d_in[6], d_in[8],
                               d_in[3], d_in[5], d_in[7],
                               w1m, w2m, wrf, wpb, b1f, b2f, rbf, flag);
  conv_mfma<1><<<dim3(6,48,8),128,0,stream>>>(X1, w1m, b1f, H1);
  conv_mfma<2><<<dim3(6,48,8),256,0,stream>>>(H1, w2m, b2f, C2);
  redir_k<<<576,256,0,stream>>>(C2, wrf, rbf, X);
  corr_k<<<dim3(16128),128,0,stream>>>(C2, X);
  final_k<<<dim3(192,4),192,0,stream>>>(X, wpb, d_out, flag);
}

// Round 3
// 776.447 us; speedup vs baseline: 1.1811x; 1.1811x over previous
//
#include <hip/hip_runtime.h>
#include <hip/hip_bf16.h>

#define HH 192
#define WW 192
#define HW (HH*WW)

typedef unsigned short u16;
typedef __attribute__((ext_vector_type(8))) short short8;
typedef __attribute__((ext_vector_type(16))) float float16;

__device__ __forceinline__ float b2f(u16 u){
  union { unsigned int i; float f; } v; v.i = ((unsigned int)u) << 16; return v.f;
}
__device__ __forceinline__ u16 f2b(float f){
  union { unsigned int i; float f; } v; v.f = f;
  unsigned int r = v.i + 0x7FFFu + ((v.i >> 16) & 1u);
  return (u16)(r >> 16);
}
__device__ __forceinline__ void up2(unsigned int w, float& lo, float& hi){
  union { unsigned int i; float f; } a, b;
  a.i = w << 16; b.i = w & 0xFFFF0000u;
  lo = a.f; hi = b.f;
}
__device__ __forceinline__ float lrelu(float x){ return x >= 0.f ? x : 0.1f*x; }
__device__ __forceinline__ float ldmix(const void* p, int i, bool bf){
  return bf ? b2f(((const u16*)p)[i]) : ((const float*)p)[i];
}

using bf2 = __attribute__((ext_vector_type(2))) __bf16;
__device__ __forceinline__ float dot2bf(unsigned int a, unsigned int b, float c){
#if __has_builtin(__builtin_amdgcn_fdot2_f32_bf16)
  union { unsigned int u; bf2 v; } ua, ub; ua.u = a; ub.u = b;
  return __builtin_amdgcn_fdot2_f32_bf16(ua.v, ub.v, c, false);
#else
  float al,ah,bl,bh; up2(a,al,ah); up2(b,bl,bh);
  return c + al*bl + ah*bh;
#endif
}

union AU { uint4 q; short8 s; };
__device__ __forceinline__ short8 s8(const uint4& q){ AU u; u.q = q; return u.s; }

#define VMCNT0 asm volatile("s_waitcnt vmcnt(0)" ::: "memory")
#define BARRIER do{ asm volatile("" ::: "memory"); __builtin_amdgcn_s_barrier(); asm volatile("" ::: "memory"); }while(0)

typedef const __attribute__((address_space(1))) unsigned char* gp1;
typedef __attribute__((address_space(3))) unsigned char* lp3;
__device__ __forceinline__ void gll16(const void* g, void* l){
  __builtin_amdgcn_global_load_lds((gp1)g, (lp3)l, 16, 0, 0);
}

__global__ __launch_bounds__(256) void detect_k(const unsigned int* __restrict__ w, int* __restrict__ flag){
  __shared__ int cnt;
  if (threadIdx.x == 0) cnt = 0;
  __syncthreads();
  unsigned int v = w[(size_t)threadIdx.x * 1024];
  int e = (v >> 7) & 0xFF;
  bool ok = ((v & 0xFFFFu) == 0u) || (e > 100 && e < 150);
  if (ok) atomicAdd(&cnt, 1);
  __syncthreads();
  if (threadIdx.x == 0) *flag = (cnt >= 192) ? 1 : 0;
}

// NCHW (fp32 or bf16) -> NHWC bf16 [8][HW][64] via LDS transpose tile.
__global__ __launch_bounds__(256) void cvt_t(const void* __restrict__ pred, const void* __restrict__ refp,
                                             u16* __restrict__ X1, const int* __restrict__ flag){
  __shared__ u16 t[64*72];
  int tid = threadIdx.x;
  int px0 = blockIdx.x*64, img = blockIdx.y;
  bool bf = (*flag != 0);
  const void* src = (img < 4) ? pred : refp;
  int im = (img < 4) ? img : img - 4;
  for (int e = tid; e < 4096; e += 256){
    int ch = e >> 6, px = e & 63;
    t[px*72 + ch] = f2b(ldmix(src, (im*64 + ch)*HW + px0 + px, bf));
  }
  __syncthreads();
  int px = tid >> 2, q = tid & 3;
  uint4 v0 = *(const uint4*)(t + px*72 + q*16);
  uint4 v1 = *(const uint4*)(t + px*72 + q*16 + 8);
  u16* dst = X1 + ((size_t)img*HW + px0 + px)*64 + q*16;
  *(uint4*)dst = v0;
  *(uint4*)(dst + 8) = v1;
}

// Weight prep (+ zero-pad scratch for corr staging).
__global__ __launch_bounds__(256) void prep_w(const void* __restrict__ w1, const void* __restrict__ w2,
                                              const void* __restrict__ wr, const void* __restrict__ wp,
                                              const void* __restrict__ b1, const void* __restrict__ b2,
                                              const void* __restrict__ rb,
                                              u16* __restrict__ w1m, u16* __restrict__ w2m,
                                              float* __restrict__ wrf, unsigned int* __restrict__ wpb,
                                              float* __restrict__ b1f, float* __restrict__ b2f,
                                              float* __restrict__ rbf, unsigned int* __restrict__ zp,
                                              const int* __restrict__ flag){
  int i = blockIdx.x*256 + threadIdx.x;
  bool bf = (*flag != 0);
  if (i < 36864){
    int j = i & 7, lane = (i>>3) & 63, cot = (i>>9) & 1, ks = (i>>10) & 3, tap = i >> 12;
    int co = cot*32 + (lane & 31), ci = ks*16 + (lane>>5)*8 + j;
    w1m[i] = f2b(ldmix(w1, (co*64 + ci)*9 + tap, bf));
  }
  if (i < 73728){
    int j = i & 7, lane = (i>>3) & 63, cot = (i>>9) & 3, ks = (i>>11) & 3, tap = i >> 13;
    int co = cot*32 + (lane & 31), ci = ks*16 + (lane>>5)*8 + j;
    w2m[i] = f2b(ldmix(w2, (co*64 + ci)*9 + tap, bf));
  }
  if (i < 4096){ int co = i & 31; int ci = i >> 5;
    wrf[ci*32+co] = ldmix(wr, co*128+ci, bf); }
  if (i < 4266){
    int cp = i/18; int rr = i - cp*18; int tap = rr >> 1; int o = rr & 1;
    int c0 = 2*cp, c1 = c0 + 1;
    float f0 = ldmix(wp, (o*473+c0)*9+tap, bf);
    float f1 = (c1 < 473) ? ldmix(wp, (o*473+c1)*9+tap, bf) : 0.f;
    wpb[i] = (unsigned int)f2b(f0) | ((unsigned int)f2b(f1) << 16);
  }
  if (i < 64)  b1f[i] = ldmix(b1, i, bf);
  if (i < 128) b2f[i] = ldmix(b2, i, bf);
  if (i < 32)  rbf[i] = ldmix(rb, i, bf);
  if (i < 128) zp[i] = 0u;
}

// MFMA implicit-GEMM 3x3 conv, pad=1, NHWC bf16 in/out, bias+lrelu.
template<int WCO>
__global__ __launch_bounds__(WCO*128) void conv_mfma(const u16* __restrict__ in, const u16* __restrict__ wm,
                                                     const float* __restrict__ bias, u16* __restrict__ out){
  constexpr int COUT = WCO*64;
  constexpr int NCOT = WCO*2;
  constexpr int THREADS = WCO*128;
  constexpr int CO_PAD = COUT + 8;
  constexpr int SLAB = 6*34*72;            // 14688 u16
  constexpr int OT   = 128*CO_PAD;
  __shared__ __align__(16) u16 smem[(SLAB > OT) ? SLAB : OT];

  int tid = threadIdx.x, lane = tid & 63, w = tid >> 6;
  int wr = w & 1, wc = w >> 1;
  int n = lane & 31, kh = lane >> 5;
  int x0 = blockIdx.x*32, y0 = blockIdx.y*4, img = blockIdx.z;
  const u16* inb = in + (size_t)img*HW*64;

  float16 acc[2][2];
  #pragma unroll
  for (int t=0;t<2;t++)
    #pragma unroll
    for (int c=0;c<2;c++)
      #pragma unroll
      for (int k=0;k<16;k++) acc[t][c][k] = 0.f;

  for (int e = tid; e < 1632; e += THREADS){
    int c8 = e & 7; int pp = e >> 3;
    int row = pp / 34, pos = pp - row*34;
    int gy = y0 + row - 1, gx = x0 + pos - 1;
    uint4 v = make_uint4(0,0,0,0);
    if (gy >= 0 && gy < HH && gx >= 0 && gx < WW)
      v = *(const uint4*)(inb + ((size_t)gy*WW + gx)*64 + c8*8);
    *(uint4*)(smem + pp*72 + c8*8) = v;
  }
  __syncthreads();

  union BU { uint2 u[2]; short8 s; };

  #pragma unroll 1
  for (int ky = 0; ky < 3; ++ky){
    #pragma unroll 1
    for (int kx = 0; kx < 3; ++kx){
      int tap = ky*3 + kx;
      #pragma unroll
      for (int ks = 0; ks < 4; ++ks){
        AU a0, a1;
        const u16* wmp = wm + (((size_t)(tap*4 + ks)*NCOT + wc*2)*64 + lane)*8;
        a0.q = *(const uint4*)(wmp);
        a1.q = *(const uint4*)(wmp + 512);
        #pragma unroll
        for (int t = 0; t < 2; ++t){
          int row = wr*2 + t + ky;
          int off = (row*34 + n + kx)*72 + ks*16 + kh*8;
          BU b;
          b.u[0] = *(const uint2*)(smem + off);
          b.u[1] = *(const uint2*)(smem + off + 4);
          acc[t][0] = __builtin_amdgcn_mfma_f32_32x32x16_bf16(a0.s, b.s, acc[t][0], 0, 0, 0);
          acc[t][1] = __builtin_amdgcn_mfma_f32_32x32x16_bf16(a1.s, b.s, acc[t][1], 0, 0, 0);
        }
      }
    }
  }

  __syncthreads();
  #pragma unroll
  for (int t = 0; t < 2; ++t){
    int pxl = (wr*2 + t)*32 + n;
    #pragma unroll
    for (int c = 0; c < 2; ++c){
      int cob = wc*64 + c*32 + 4*kh;
      #pragma unroll
      for (int p = 0; p < 8; ++p){
        int co = cob + (p&1)*2 + (p>>1)*8;
        float2 bb = *(const float2*)(bias + co);
        float v0 = lrelu(acc[t][c][2*p]   + bb.x);
        float v1 = lrelu(acc[t][c][2*p+1] + bb.y);
        unsigned int pk = (unsigned int)f2b(v0) | ((unsigned int)f2b(v1) << 16);
        *(unsigned int*)(smem + pxl*CO_PAD + co) = pk;
      }
    }
  }
  __syncthreads();
  int px, part;
  if (WCO == 2){ px = tid >> 1; part = tid & 1; } else { px = tid; part = 0; }
  const u16* sp = smem + px*CO_PAD + part*64;
  u16* gp = out + ((size_t)img*HW + (size_t)(y0 + (px>>5))*WW + x0 + (px&31))*COUT + part*64;
  #pragma unroll
  for (int k = 0; k < 8; ++k)
    *(uint4*)(gp + k*8) = *(const uint4*)(sp + k*8);
}

// 1x1 redir conv (128->32) + bias + lrelu. X NCHW [b][473][HW]; planes 0..31.
__global__ __launch_bounds__(256) void redir_k(const u16* __restrict__ C2, const float* __restrict__ wrf,
                                               const float* __restrict__ rbf, u16* __restrict__ X){
  int p = blockIdx.x*256 + threadIdx.x;
  int b = p / HW; int pix = p - b*HW;
  const u16* ap = C2 + (size_t)p*128;
  float acc[32];
  #pragma unroll
  for (int j=0;j<32;j++) acc[j]=0.f;
  for (int ci=0; ci<128; ci+=4){
    uint2 aw = *(const uint2*)(ap + ci);
    float a0,a1,a2,a3;
    up2(aw.x,a0,a1); up2(aw.y,a2,a3);
    const float* w0 = wrf + ci*32;
    #pragma unroll
    for (int co=0; co<32; co+=4){
      float4 wv0 = *(const float4*)(w0+co);
      float4 wv1 = *(const float4*)(w0+32+co);
      float4 wv2 = *(const float4*)(w0+64+co);
      float4 wv3 = *(const float4*)(w0+96+co);
      acc[co+0] += a0*wv0.x + a1*wv1.x + a2*wv2.x + a3*wv3.x;
      acc[co+1] += a0*wv0.y + a1*wv1.y + a2*wv2.y + a3*wv3.y;
      acc[co+2] += a0*wv0.z + a1*wv1.z + a2*wv2.z + a3*wv3.z;
      acc[co+3] += a0*wv0.w + a1*wv1.w + a2*wv2.w + a3*wv3.w;
    }
  }
  #pragma unroll
  for (int co=0; co<32; ++co){
    X[(size_t)(b*473 + co)*HW + pix] = f2b(lrelu(acc[co] + rbf[co]));
  }
}

// ---------------------------------------------------------------------------
// Correlation, round 9: banded-GEMM on MFMA.
// Block = (b, y), 256 thr (4 waves). Waves 0-2 own 64 x each; wave 3 is
// producer/storer. For each dy: C[x,z] = sum_c A[y,x,c]*B[r,z,c], |z-x|<=20.
// Per wave: 2 x-tiles (32) x 3 z-tiles from 4 staged, 32x32x16 MFMA, K=128
// split in two halves. A-frags preloaded from global into 64 VGPRs (reused
// across all dy). B row staged into LDS [256 pos][64ch] per (dy,kh) via
// global_load_lds with pre-swizzled per-lane source (XOR (pos&7) on 16B slot;
// linear LDS dest) -> conflict-free ds_read_b128 frags. Double-buffered,
// vmcnt(0)+raw s_barrier per step. OOB z lanes read a zeroed scratch (zp).
// Epilogue: band elements of acc -> E[dy&1][21][192] in LDS; wave 3 streams
// E(dy-1) to global during dy's first step and zeroes OOB-dy planes.
// Grid 768 = 8 XCDs x 96 (bijective swizzle): b-rows stay L2-hot across y.
// ---------------------------------------------------------------------------
template<int KH>
__device__ __forceinline__ void corr_step(const unsigned char* __restrict__ Bb, int xb, int zl, int hi,
                                          const uint4 (&a)[2][8], float16 (&acc)[2][3]){
  uint4 bf[4][4];
  #pragma unroll
  for (int k = 0; k < 4; ++k){
    #pragma unroll
    for (int ksl = 0; ksl < 4; ++ksl){
      int pos = xb + 32*k + zl;
      int slot = (ksl*2 + hi) ^ (pos & 7);
      bf[k][ksl] = *(const uint4*)(Bb + pos*128 + slot*16);
    }
  }
  #pragma unroll
  for (int ksl = 0; ksl < 4; ++ksl){
    #pragma unroll
    for (int xt = 0; xt < 2; ++xt){
      #pragma unroll
      for (int j = 0; j < 3; ++j){
        acc[xt][j] = __builtin_amdgcn_mfma_f32_32x32x16_bf16(
            s8(a[xt][KH*4 + ksl]), s8(bf[xt+j][ksl]), acc[xt][j], 0, 0, 0);
      }
    }
  }
}

__global__ __launch_bounds__(256,2) void corr_k(const u16* __restrict__ C2, u16* __restrict__ X,
                                                const unsigned int* __restrict__ zp){
  __shared__ __align__(16) unsigned char smB[2][32768];   // [buf][256 pos][8 slot][16B]
  __shared__ __align__(16) u16 smE[2][21][192];

  int bid = blockIdx.x;
  int v = (bid & 7)*96 + (bid >> 3);      // XCD-contiguous, bijective (768 = 8*96)
  int b = v / 192, y = v - b*192;

  int tid = threadIdx.x, lane = tid & 63, w = tid >> 6;
  int zl = lane & 31, hi = lane >> 5;
  int xb = w * 64;

  int dylo = max(0, (21 - y) >> 1);
  int dyhi = min(20, (211 - y) >> 1);

  const unsigned char* Ab   = (const unsigned char*)(C2 + ((size_t)b*HW + (size_t)y*WW)*128);
  const unsigned char* Bimg = (const unsigned char*)(C2 + ((size_t)(b+4)*HW)*128);
  u16* Xb = X + ((size_t)(b*473 + 32))*HW + (size_t)y*WW;

  uint4 a[2][8];
  float16 acc[2][3];
  if (w < 3){
    #pragma unroll
    for (int xt = 0; xt < 2; ++xt)
      #pragma unroll
      for (int kq = 0; kq < 8; ++kq)
        a[xt][kq] = *(const uint4*)(Ab + (size_t)(xb + xt*32 + zl)*256 + kq*32 + hi*16);
    #pragma unroll
    for (int xt = 0; xt < 2; ++xt)
      #pragma unroll
      for (int j = 0; j < 3; ++j)
        #pragma unroll
        for (int q = 0; q < 16; ++q) acc[xt][j][q] = 0.f;
  } else {
    // zero the OOB-dy planes
    for (int dz = 0; dz < 21; ++dz){
      if (dz >= dylo && dz <= dyhi) continue;
      u16* bp = Xb + (size_t)dz*21*HW;
      for (int e = lane; e < 2016; e += 64){
        int dx = e/96, xw = e - dx*96;
        *(unsigned int*)(bp + (size_t)dx*HW + xw*2) = 0u;
      }
    }
  }

  // stage B row r, k-half kh into smB[buf] (all 4 waves, 8 gll each)
  auto stage = [&](int buf, int r, int kh){
    const unsigned char* Bg = Bimg + (size_t)r*WW*256 + (size_t)kh*128;
    #pragma unroll
    for (int i = 0; i < 8; ++i){
      int t = w*8 + i;
      int q = t*64 + lane;
      int pos = q >> 3, s = q & 7;
      int z = pos - 20;
      const void* src = (z >= 0 && z < WW)
          ? (const void*)(Bg + (size_t)z*256 + ((s ^ (pos & 7)) << 4))
          : (const void*)zp;
      gll16(src, (void*)(smB[buf] + t*1024));
    }
  };

  stage(0, y + 2*dylo - 20, 0);
  VMCNT0; BARRIER;

  for (int dy = dylo; dy <= dyhi; ++dy){
    int r = y + 2*dy - 20;
    // ---- step kh=0: stage kh=1 of same row; compute kh=0; w3 stores E(dy-1)
    stage(1, r, 1);
    if (w < 3){
      corr_step<0>(smB[0], xb, zl, hi, a, acc);
    } else if (dy > dylo){
      int dyp = dy - 1;
      const unsigned int* Er = (const unsigned int*)smE[dyp & 1];
      u16* bp = Xb + (size_t)dyp*21*HW;
      for (int e = lane; e < 2016; e += 64){
        int dx = e/96, xw = e - dx*96;
        *(unsigned int*)(bp + (size_t)dx*HW + xw*2) = Er[e];
      }
    }
    VMCNT0; BARRIER;
    // ---- step kh=1: stage kh=0 of next row; compute kh=1; dump E(dy)
    if (dy + 1 <= dyhi) stage(0, r + 2, 0);
    if (w < 3){
      corr_step<1>(smB[1], xb, zl, hi, a, acc);
      int zl4 = zl - 4*hi;
      #pragma unroll
      for (int xt = 0; xt < 2; ++xt){
        #pragma unroll
        for (int j = 0; j < 3; ++j){
          #pragma unroll
          for (int reg = 0; reg < 16; ++reg){
            int regc = (reg & 3) + 8*(reg >> 2);
            int u = 32*j + zl4 - regc;
            if ((unsigned)u <= 40u && !(u & 1)){
              int x = xb + xt*32 + 4*hi + regc;
              smE[dy & 1][u >> 1][x] = f2b(lrelu(acc[xt][j][reg] * (1.f/128.f)));
            }
          }
          #pragma unroll
          for (int reg = 0; reg < 16; ++reg) acc[xt][j][reg] = 0.f;
        }
      }
    }
    VMCNT0; BARRIER;
  }

  // final E store (all threads)
  {
    const unsigned int* Er = (const unsigned int*)smE[dyhi & 1];
    u16* bp = Xb + (size_t)dyhi*21*HW;
    for (int e = tid; e < 2016; e += 256){
      int dx = e/96, xw = e - dx*96;
      *(unsigned int*)(bp + (size_t)dx*HW + xw*2) = Er[e];
    }
  }
}

// Final 3x3 conv: contribution-passing (see round 6).
__global__ __launch_bounds__(192) void final_k(const u16* __restrict__ X, const unsigned int* __restrict__ wpb,
                                               void* __restrict__ out, const int* __restrict__ flag){
  __shared__ float eR[4][2], eL[4][2];
  int x = threadIdx.x, y = blockIdx.x, b = blockIdx.y;
  int w = x >> 6, lane = x & 63;
  const u16* Xb = X + (size_t)b*473*HW;
  float Pm0=0.f,Pm1=0.f,Pl0=0.f,Pl1=0.f,Pr0=0.f,Pr1=0.f;
  bool rok0 = (y > 0), rok2 = (y < HH-1);
  size_t off0 = (size_t)(y-1)*WW + x;
  size_t off1 = (size_t)(y  )*WW + x;
  size_t off2 = (size_t)(y+1)*WW + x;

  for (int cp = 0; cp < 237; ++cp){
    const unsigned int* w18 = wpb + cp*18;
    size_t base0 = (size_t)(2*cp)*HW;
    size_t base1 = base0 + HW;
    bool c1ok = (2*cp+1) < 473;
    #pragma unroll
    for (int r = 0; r < 3; ++r){
      bool ok = (r==0) ? rok0 : ((r==2) ? rok2 : true);
      size_t off = (r==0) ? off0 : ((r==2) ? off2 : off1);
      unsigned int v = 0;
      if (ok){
        unsigned int lo = Xb[base0 + off];
        unsigned int hi = c1ok ? (unsigned int)Xb[base1 + off] : 0u;
        v = lo | (hi << 16);
      }
      Pm0 = dot2bf(v, w18[(r*3+1)*2+0], Pm0);
      Pm1 = dot2bf(v, w18[(r*3+1)*2+1], Pm1);
      Pl0 = dot2bf(v, w18[(r*3+2)*2+0], Pl0);
      Pl1 = dot2bf(v, w18[(r*3+2)*2+1], Pl1);
      Pr0 = dot2bf(v, w18[(r*3+0)*2+0], Pr0);
      Pr1 = dot2bf(v, w18[(r*3+0)*2+1], Pr1);
    }
  }

  float r0 = __shfl_up(Pr0,1), r1 = __shfl_up(Pr1,1);
  float l0 = __shfl_down(Pl0,1), l1 = __shfl_down(Pl1,1);
  if (x == 0){ eR[0][0]=0.f; eR[0][1]=0.f; eL[3][0]=0.f; eL[3][1]=0.f; }
  if (lane == 63){ eR[w+1][0]=Pr0; eR[w+1][1]=Pr1; }
  if (lane == 0 && w > 0){ eL[w][0]=Pl0; eL[w][1]=Pl1; }
  __syncthreads();
  if (lane == 0){ r0 = eR[w][0]; r1 = eR[w][1]; }
  if (lane == 63){ l0 = eL[w+1][0]; l1 = eL[w+1][1]; }
  float a0 = Pm0 + r0 + l0;
  float a1 = Pm1 + r1 + l1;

  size_t rem = (size_t)y*WW + x;
  size_t i0 = (size_t)(b*2)*HW + rem;
  size_t i1 = (size_t)(b*2+1)*HW + rem;
  if (*flag){
    ((u16*)out)[i0] = f2b(a0);
    ((u16*)out)[i1] = f2b(a1);
  } else {
    ((float*)out)[i0] = a0;
    ((float*)out)[i1] = a1;
  }
}

// Workspace (bytes):
//   C2 [0, 75497472)           conv2 out NHWC bf16 [8][HW][128]
//   X1 [75497472, 113246208)   cvt out NHWC bf16 [8][HW][64] (dies after conv1)
//   H1 [113246208, 150994944)  conv1 out NHWC bf16 (dies after conv2)
//   X  [75497472, 214958080)   concat NCHW bf16 [4][473][HW] (overlays X1+H1)
//   zpad at 215056384 (512 B zeros, in the gap before weights)
//   weights at 215322624 (~260 KB)
extern "C" void kernel_launch(void* const* d_in, const int* in_sizes, int n_in,
                              void* d_out, int out_size, void* d_ws, size_t ws_size,
                              hipStream_t stream){
  char* ws = (char*)d_ws;
  u16* C2 = (u16*)ws;
  u16* X1 = (u16*)(ws + 75497472);
  u16* H1 = (u16*)(ws + 113246208);
  u16* X  = (u16*)(ws + 75497472);
  unsigned int* zp = (unsigned int*)(ws + 215056384);
  u16* w1m = (u16*)(ws + 215322624);
  u16* w2m = w1m + 36864;
  float* wrf = (float*)(w2m + 73728);
  unsigned int* wpb = (unsigned int*)(wrf + 4096);
  float* b1f = (float*)(wpb + 4266);
  float* b2f = b1f + 64;
  float* rbf = b2f + 128;
  int* flag  = (int*)(rbf + 32);

  detect_k<<<1,256,0,stream>>>((const unsigned int*)d_in[0], flag);
  cvt_t<<<dim3(576,8),256,0,stream>>>(d_in[0], d_in[1], X1, flag);
  prep_w<<<288,256,0,stream>>>(d_in[2], d_in[4], d_in[6], d_in[8],
                               d_in[3], d_in[5], d_in[7],
                               w1m, w2m, wrf, wpb, b1f, b2f, rbf, zp, flag);
  conv_mfma<1><<<dim3(6,48,8),128,0,stream>>>(X1, w1m, b1f, H1);
  conv_mfma<2><<<dim3(6,48,8),256,0,stream>>>(H1, w2m, b2f, C2);
  redir_k<<<576,256,0,stream>>>(C2, wrf, rbf, X);
  corr_k<<<dim3(768),256,0,stream>>>(C2, X, zp);
  final_k<<<dim3(192,4),192,0,stream>>>(X, wpb, d_out, flag);
}

// Round 4
// 625.993 us; speedup vs baseline: 1.4649x; 1.2403x over previous
//
#include <hip/hip_runtime.h>
#include <hip/hip_bf16.h>

#define HH 192
#define WW 192
#define HW (HH*WW)

typedef unsigned short u16;
typedef __attribute__((ext_vector_type(8))) short short8;
typedef __attribute__((ext_vector_type(16))) float float16;
typedef __attribute__((ext_vector_type(4))) float f32x4;

__device__ __forceinline__ float b2f(u16 u){
  union { unsigned int i; float f; } v; v.i = ((unsigned int)u) << 16; return v.f;
}
__device__ __forceinline__ u16 f2b(float f){
  union { unsigned int i; float f; } v; v.f = f;
  unsigned int r = v.i + 0x7FFFu + ((v.i >> 16) & 1u);
  return (u16)(r >> 16);
}
__device__ __forceinline__ void up2(unsigned int w, float& lo, float& hi){
  union { unsigned int i; float f; } a, b;
  a.i = w << 16; b.i = w & 0xFFFF0000u;
  lo = a.f; hi = b.f;
}
__device__ __forceinline__ float lrelu(float x){ return x >= 0.f ? x : 0.1f*x; }
__device__ __forceinline__ float ldmix(const void* p, int i, bool bf){
  return bf ? b2f(((const u16*)p)[i]) : ((const float*)p)[i];
}

using bf2 = __attribute__((ext_vector_type(2))) __bf16;
__device__ __forceinline__ float dot2bf(unsigned int a, unsigned int b, float c){
#if __has_builtin(__builtin_amdgcn_fdot2_f32_bf16)
  union { unsigned int u; bf2 v; } ua, ub; ua.u = a; ub.u = b;
  return __builtin_amdgcn_fdot2_f32_bf16(ua.v, ub.v, c, false);
#else
  float al,ah,bl,bh; up2(a,al,ah); up2(b,bl,bh);
  return c + al*bl + ah*bh;
#endif
}

union AU { uint4 q; short8 s; };
__device__ __forceinline__ short8 s8(const uint4& q){ AU u; u.q = q; return u.s; }

__global__ __launch_bounds__(256) void detect_k(const unsigned int* __restrict__ w, int* __restrict__ flag){
  __shared__ int cnt;
  if (threadIdx.x == 0) cnt = 0;
  __syncthreads();
  unsigned int v = w[(size_t)threadIdx.x * 1024];
  int e = (v >> 7) & 0xFF;
  bool ok = ((v & 0xFFFFu) == 0u) || (e > 100 && e < 150);
  if (ok) atomicAdd(&cnt, 1);
  __syncthreads();
  if (threadIdx.x == 0) *flag = (cnt >= 192) ? 1 : 0;
}

// NCHW (fp32 or bf16) -> NHWC bf16 [8][HW][64] via LDS transpose tile.
__global__ __launch_bounds__(256) void cvt_t(const void* __restrict__ pred, const void* __restrict__ refp,
                                             u16* __restrict__ X1, const int* __restrict__ flag){
  __shared__ u16 t[64*72];
  int tid = threadIdx.x;
  int px0 = blockIdx.x*64, img = blockIdx.y;
  bool bf = (*flag != 0);
  const void* src = (img < 4) ? pred : refp;
  int im = (img < 4) ? img : img - 4;
  for (int e = tid; e < 4096; e += 256){
    int ch = e >> 6, px = e & 63;
    t[px*72 + ch] = f2b(ldmix(src, (im*64 + ch)*HW + px0 + px, bf));
  }
  __syncthreads();
  int px = tid >> 2, q = tid & 3;
  uint4 v0 = *(const uint4*)(t + px*72 + q*16);
  uint4 v1 = *(const uint4*)(t + px*72 + q*16 + 8);
  u16* dst = X1 + ((size_t)img*HW + px0 + px)*64 + q*16;
  *(uint4*)dst = v0;
  *(uint4*)(dst + 8) = v1;
}

// Weight prep.
__global__ __launch_bounds__(256) void prep_w(const void* __restrict__ w1, const void* __restrict__ w2,
                                              const void* __restrict__ wr, const void* __restrict__ wp,
                                              const void* __restrict__ b1, const void* __restrict__ b2,
                                              const void* __restrict__ rb,
                                              u16* __restrict__ w1m, u16* __restrict__ w2m,
                                              float* __restrict__ wrf, unsigned int* __restrict__ wpb,
                                              float* __restrict__ b1f, float* __restrict__ b2f,
                                              float* __restrict__ rbf, const int* __restrict__ flag){
  int i = blockIdx.x*256 + threadIdx.x;
  bool bf = (*flag != 0);
  if (i < 36864){
    int j = i & 7, lane = (i>>3) & 63, cot = (i>>9) & 1, ks = (i>>10) & 3, tap = i >> 12;
    int co = cot*32 + (lane & 31), ci = ks*16 + (lane>>5)*8 + j;
    w1m[i] = f2b(ldmix(w1, (co*64 + ci)*9 + tap, bf));
  }
  if (i < 73728){
    int j = i & 7, lane = (i>>3) & 63, cot = (i>>9) & 3, ks = (i>>11) & 3, tap = i >> 13;
    int co = cot*32 + (lane & 31), ci = ks*16 + (lane>>5)*8 + j;
    w2m[i] = f2b(ldmix(w2, (co*64 + ci)*9 + tap, bf));
  }
  if (i < 4096){ int co = i & 31; int ci = i >> 5;
    wrf[ci*32+co] = ldmix(wr, co*128+ci, bf); }
  if (i < 4266){
    int cp = i/18; int rr = i - cp*18; int tap = rr >> 1; int o = rr & 1;
    int c0 = 2*cp, c1 = c0 + 1;
    float f0 = ldmix(wp, (o*473+c0)*9+tap, bf);
    float f1 = (c1 < 473) ? ldmix(wp, (o*473+c1)*9+tap, bf) : 0.f;
    wpb[i] = (unsigned int)f2b(f0) | ((unsigned int)f2b(f1) << 16);
  }
  if (i < 64)  b1f[i] = ldmix(b1, i, bf);
  if (i < 128) b2f[i] = ldmix(b2, i, bf);
  if (i < 32)  rbf[i] = ldmix(rb, i, bf);
}

// MFMA implicit-GEMM 3x3 conv, pad=1, NHWC bf16 in/out, bias+lrelu.
template<int WCO>
__global__ __launch_bounds__(WCO*128) void conv_mfma(const u16* __restrict__ in, const u16* __restrict__ wm,
                                                     const float* __restrict__ bias, u16* __restrict__ out){
  constexpr int COUT = WCO*64;
  constexpr int NCOT = WCO*2;
  constexpr int THREADS = WCO*128;
  constexpr int CO_PAD = COUT + 8;
  constexpr int SLAB = 6*34*72;            // 14688 u16
  constexpr int OT   = 128*CO_PAD;
  __shared__ __align__(16) u16 smem[(SLAB > OT) ? SLAB : OT];

  int tid = threadIdx.x, lane = tid & 63, w = tid >> 6;
  int wr = w & 1, wc = w >> 1;
  int n = lane & 31, kh = lane >> 5;
  int x0 = blockIdx.x*32, y0 = blockIdx.y*4, img = blockIdx.z;
  const u16* inb = in + (size_t)img*HW*64;

  float16 acc[2][2];
  #pragma unroll
  for (int t=0;t<2;t++)
    #pragma unroll
    for (int c=0;c<2;c++)
      #pragma unroll
      for (int k=0;k<16;k++) acc[t][c][k] = 0.f;

  for (int e = tid; e < 1632; e += THREADS){
    int c8 = e & 7; int pp = e >> 3;
    int row = pp / 34, pos = pp - row*34;
    int gy = y0 + row - 1, gx = x0 + pos - 1;
    uint4 v = make_uint4(0,0,0,0);
    if (gy >= 0 && gy < HH && gx >= 0 && gx < WW)
      v = *(const uint4*)(inb + ((size_t)gy*WW + gx)*64 + c8*8);
    *(uint4*)(smem + pp*72 + c8*8) = v;
  }
  __syncthreads();

  union BU { uint2 u[2]; short8 s; };

  #pragma unroll 1
  for (int ky = 0; ky < 3; ++ky){
    #pragma unroll 1
    for (int kx = 0; kx < 3; ++kx){
      int tap = ky*3 + kx;
      #pragma unroll
      for (int ks = 0; ks < 4; ++ks){
        AU a0, a1;
        const u16* wmp = wm + (((size_t)(tap*4 + ks)*NCOT + wc*2)*64 + lane)*8;
        a0.q = *(const uint4*)(wmp);
        a1.q = *(const uint4*)(wmp + 512);
        #pragma unroll
        for (int t = 0; t < 2; ++t){
          int row = wr*2 + t + ky;
          int off = (row*34 + n + kx)*72 + ks*16 + kh*8;
          BU b;
          b.u[0] = *(const uint2*)(smem + off);
          b.u[1] = *(const uint2*)(smem + off + 4);
          acc[t][0] = __builtin_amdgcn_mfma_f32_32x32x16_bf16(a0.s, b.s, acc[t][0], 0, 0, 0);
          acc[t][1] = __builtin_amdgcn_mfma_f32_32x32x16_bf16(a1.s, b.s, acc[t][1], 0, 0, 0);
        }
      }
    }
  }

  __syncthreads();
  #pragma unroll
  for (int t = 0; t < 2; ++t){
    int pxl = (wr*2 + t)*32 + n;
    #pragma unroll
    for (int c = 0; c < 2; ++c){
      int cob = wc*64 + c*32 + 4*kh;
      #pragma unroll
      for (int p = 0; p < 8; ++p){
        int co = cob + (p&1)*2 + (p>>1)*8;
        float2 bb = *(const float2*)(bias + co);
        float v0 = lrelu(acc[t][c][2*p]   + bb.x);
        float v1 = lrelu(acc[t][c][2*p+1] + bb.y);
        unsigned int pk = (unsigned int)f2b(v0) | ((unsigned int)f2b(v1) << 16);
        *(unsigned int*)(smem + pxl*CO_PAD + co) = pk;
      }
    }
  }
  __syncthreads();
  int px, part;
  if (WCO == 2){ px = tid >> 1; part = tid & 1; } else { px = tid; part = 0; }
  const u16* sp = smem + px*CO_PAD + part*64;
  u16* gp = out + ((size_t)img*HW + (size_t)(y0 + (px>>5))*WW + x0 + (px&31))*COUT + part*64;
  #pragma unroll
  for (int k = 0; k < 8; ++k)
    *(uint4*)(gp + k*8) = *(const uint4*)(sp + k*8);
}

// 1x1 redir conv (128->32) + bias + lrelu. X NCHW [b][473][HW]; planes 0..31.
__global__ __launch_bounds__(256) void redir_k(const u16* __restrict__ C2, const float* __restrict__ wrf,
                                               const float* __restrict__ rbf, u16* __restrict__ X){
  int p = blockIdx.x*256 + threadIdx.x;
  int b = p / HW; int pix = p - b*HW;
  const u16* ap = C2 + (size_t)p*128;
  float acc[32];
  #pragma unroll
  for (int j=0;j<32;j++) acc[j]=0.f;
  for (int ci=0; ci<128; ci+=4){
    uint2 aw = *(const uint2*)(ap + ci);
    float a0,a1,a2,a3;
    up2(aw.x,a0,a1); up2(aw.y,a2,a3);
    const float* w0 = wrf + ci*32;
    #pragma unroll
    for (int co=0; co<32; co+=4){
      float4 wv0 = *(const float4*)(w0+co);
      float4 wv1 = *(const float4*)(w0+32+co);
      float4 wv2 = *(const float4*)(w0+64+co);
      float4 wv3 = *(const float4*)(w0+96+co);
      acc[co+0] += a0*wv0.x + a1*wv1.x + a2*wv2.x + a3*wv3.x;
      acc[co+1] += a0*wv0.y + a1*wv1.y + a2*wv2.y + a3*wv3.y;
      acc[co+2] += a0*wv0.z + a1*wv1.z + a2*wv2.z + a3*wv3.z;
      acc[co+3] += a0*wv0.w + a1*wv1.w + a2*wv2.w + a3*wv3.w;
    }
  }
  #pragma unroll
  for (int co=0; co<32; ++co){
    X[(size_t)(b*473 + co)*HW + pix] = f2b(lrelu(acc[co] + rbf[co]));
  }
}

// Zero the orphan (y,dy) plane rows (r = y+2dy-20 outside [0,192)).
__global__ __launch_bounds__(256) void zero_k(u16* __restrict__ X){
  int yi = blockIdx.x, b = blockIdx.y;
  int y = (yi < 20) ? yi : 152 + yi;           // y in [0,20) or [172,192)
  int locnt = (yi < 20) ? ((21 - y) >> 1) : 0; // orphan dy = 0..locnt-1
  int hi0 = (213 - y) >> 1;                    // first orphan dy at high end
  int hicnt = (yi < 20) ? 0 : (21 - hi0);
  int ncnt = locnt + hicnt;
  u16* Xb = X + ((size_t)(b*473 + 32))*HW + (size_t)y*WW;
  int total = ncnt*2016;
  for (int e = threadIdx.x; e < total; e += 256){
    int i = e / 2016, rem = e - i*2016;
    int dy = (i < locnt) ? i : (hi0 + i - locnt);
    int d = rem / 96, xw = rem - d*96;
    *(unsigned int*)(Xb + ((size_t)(dy*21 + d))*HW + 2*xw) = 0u;
  }
}

// ---------------------------------------------------------------------------
// Correlation, round 10: B-row-centric, parity-packed 16x16x32 MFMA, no LDS
// staging. Block = (b, r). The B row r (192 px x 128 ch) is loaded ONCE into
// MFMA B-frags in registers (predicated global loads, zeros OOB) and reused
// for all y = r+20-2dy, dy in [dylo,dyhi]. Since z-x is even, the problem
// splits by parity: u = x>>1, z' = z>>1, band |z'-u|<=10. 4 waves: w ->
// (parity p=w&1, u-range [48*(w>>1), +48)), 3 u-tiles of 16, z-tiles at
// ut-16, ut, ut+16 (5 unique B-frags/wave). 36 mfma_16x16x32 per wave per y
// (44% band utilization). A row streamed global->reg per y (L2-hot: shared
// by 21 neighbor-r blocks on the same XCD via bijective swizzle 768=8*96),
// prefetched after compute so the E-phase hides its latency.
// E epilogue: band extract (d = z'-u+10) -> smE rows stride 198 u16 (odd dw
// stride -> conflict-free) -> coop dword store (full-line coverage).
// Orphan (y,dy) handled by zero_k.
// ---------------------------------------------------------------------------
__global__ __launch_bounds__(256,2) void corr_k(const u16* __restrict__ C2, u16* __restrict__ X){
  __shared__ __align__(16) u16 smE[4160];

  int bid = blockIdx.x;
  int v = (bid & 7)*96 + (bid >> 3);       // XCD-contiguous, bijective (768 = 8*96)
  int b = v / 192, r = v - b*192;

  int tid = threadIdx.x, lane = tid & 63, w = tid >> 6;
  int n = lane & 15, s = lane >> 4;
  int p = w & 1, u0w = (w >> 1)*48;

  const u16* Brow = C2 + ((size_t)(b+4)*HW + (size_t)r*WW)*128;
  const u16* Aimg = C2 + (size_t)b*HW*128;

  // B-frags, held in regs for the whole kernel. bf[kk][l]: K-step kk (32ch),
  // z-tile l (z' = u0w-16+16l + n). Lane: n = z-col, s -> ch granule.
  uint4 bf[4][5];
  #pragma unroll
  for (int l = 0; l < 5; ++l){
    int zq = u0w + 16*l + n - 16;
    bool vz = ((unsigned)zq < 96u);
    const u16* bp = Brow + (long)(2*zq + p)*128;
    #pragma unroll
    for (int kk = 0; kk < 4; ++kk){
      uint4 t0 = make_uint4(0,0,0,0);
      if (vz) t0 = *(const uint4*)(bp + (kk*4 + s)*8);
      bf[kk][l] = t0;
    }
  }

  int dylo = max(0, (r-170)>>1);
  int dyhi = min(20, (r+20)>>1);

  uint4 A[3][4];
  f32x4 acc[3][3];

  auto loadA = [&](int yy){
    const u16* Ay = Aimg + (size_t)yy*WW*128;
    #pragma unroll
    for (int t = 0; t < 3; ++t){
      const u16* apx = Ay + (size_t)(2*(u0w + 16*t + n) + p)*128;
      #pragma unroll
      for (int kk = 0; kk < 4; ++kk)
        A[t][kk] = *(const uint4*)(apx + (kk*4 + s)*8);
    }
  };

  int nm6 = n - 4*s - 6;
  auto eout = [&](int yy, int dyy){
    // band extract: d = 16(j-1) + n - m + 10, m = 4s+q; x = 2(ut+m)+p
    #pragma unroll
    for (int t = 0; t < 3; ++t){
      int xb2 = 2*(u0w + 16*t) + p + 8*s;
      #pragma unroll
      for (int j = 0; j < 3; ++j){
        #pragma unroll
        for (int q = 0; q < 4; ++q){
          int dd = nm6 - q + 16*j;
          if ((unsigned)dd <= 20u){
            float val = acc[t][j][q]*(1.f/128.f);
            val = fmaxf(val, 0.f) + 0.1f*fminf(val, 0.f);
            smE[dd*198 + xb2 + 2*q] = f2b(val);
          }
        }
      }
    }
    __syncthreads();
    u16* Xp = X + ((size_t)(b*473 + 32 + dyy*21))*HW + (size_t)yy*WW;
    #pragma unroll
    for (int e0 = 0; e0 < 8; ++e0){
      int e = e0*256 + tid;
      if (e < 2016){
        int d = e/96, xw = e - d*96;
        *(unsigned int*)(Xp + (size_t)d*HW + 2*xw) = *(const unsigned int*)(smE + d*198 + 2*xw);
      }
    }
    __syncthreads();
  };

  loadA(r + 20 - 2*dylo);

  #pragma unroll 1
  for (int dy = dylo; dy <= dyhi; ++dy){
    int y = r + 20 - 2*dy;
    if (dy > dylo) eout(y + 2, dy - 1);
    #pragma unroll
    for (int t = 0; t < 3; ++t)
      #pragma unroll
      for (int j = 0; j < 3; ++j)
        acc[t][j] = (f32x4){0.f, 0.f, 0.f, 0.f};
    #pragma unroll
    for (int kk = 0; kk < 4; ++kk)
      #pragma unroll
      for (int t = 0; t < 3; ++t)
        #pragma unroll
        for (int j = 0; j < 3; ++j)
          acc[t][j] = __builtin_amdgcn_mfma_f32_16x16x32_bf16(
              s8(A[t][kk]), s8(bf[kk][t+j]), acc[t][j], 0, 0, 0);
    if (dy < dyhi) loadA(y - 2);
  }
  eout(r + 20 - 2*dyhi, dyhi);
}

// Final 3x3 conv: contribution-passing (see round 6).
__global__ __launch_bounds__(192) void final_k(const u16* __restrict__ X, const unsigned int* __restrict__ wpb,
                                               void* __restrict__ out, const int* __restrict__ flag){
  __shared__ float eR[4][2], eL[4][2];
  int x = threadIdx.x, y = blockIdx.x, b = blockIdx.y;
  int w = x >> 6, lane = x & 63;
  const u16* Xb = X + (size_t)b*473*HW;
  float Pm0=0.f,Pm1=0.f,Pl0=0.f,Pl1=0.f,Pr0=0.f,Pr1=0.f;
  bool rok0 = (y > 0), rok2 = (y < HH-1);
  size_t off0 = (size_t)(y-1)*WW + x;
  size_t off1 = (size_t)(y  )*WW + x;
  size_t off2 = (size_t)(y+1)*WW + x;

  for (int cp = 0; cp < 237; ++cp){
    const unsigned int* w18 = wpb + cp*18;
    size_t base0 = (size_t)(2*cp)*HW;
    size_t base1 = base0 + HW;
    bool c1ok = (2*cp+1) < 473;
    #pragma unroll
    for (int r = 0; r < 3; ++r){
      bool ok = (r==0) ? rok0 : ((r==2) ? rok2 : true);
      size_t off = (r==0) ? off0 : ((r==2) ? off2 : off1);
      unsigned int v = 0;
      if (ok){
        unsigned int lo = Xb[base0 + off];
        unsigned int hi = c1ok ? (unsigned int)Xb[base1 + off] : 0u;
        v = lo | (hi << 16);
      }
      Pm0 = dot2bf(v, w18[(r*3+1)*2+0], Pm0);
      Pm1 = dot2bf(v, w18[(r*3+1)*2+1], Pm1);
      Pl0 = dot2bf(v, w18[(r*3+2)*2+0], Pl0);
      Pl1 = dot2bf(v, w18[(r*3+2)*2+1], Pl1);
      Pr0 = dot2bf(v, w18[(r*3+0)*2+0], Pr0);
      Pr1 = dot2bf(v, w18[(r*3+0)*2+1], Pr1);
    }
  }

  float r0 = __shfl_up(Pr0,1), r1 = __shfl_up(Pr1,1);
  float l0 = __shfl_down(Pl0,1), l1 = __shfl_down(Pl1,1);
  if (x == 0){ eR[0][0]=0.f; eR[0][1]=0.f; eL[3][0]=0.f; eL[3][1]=0.f; }
  if (lane == 63){ eR[w+1][0]=Pr0; eR[w+1][1]=Pr1; }
  if (lane == 0 && w > 0){ eL[w][0]=Pl0; eL[w][1]=Pl1; }
  __syncthreads();
  if (lane == 0){ r0 = eR[w][0]; r1 = eR[w][1]; }
  if (lane == 63){ l0 = eL[w+1][0]; l1 = eL[w+1][1]; }
  float a0 = Pm0 + r0 + l0;
  float a1 = Pm1 + r1 + l1;

  size_t rem = (size_t)y*WW + x;
  size_t i0 = (size_t)(b*2)*HW + rem;
  size_t i1 = (size_t)(b*2+1)*HW + rem;
  if (*flag){
    ((u16*)out)[i0] = f2b(a0);
    ((u16*)out)[i1] = f2b(a1);
  } else {
    ((float*)out)[i0] = a0;
    ((float*)out)[i1] = a1;
  }
}

// Workspace (bytes):
//   C2 [0, 75497472)           conv2 out NHWC bf16 [8][HW][128]
//   X1 [75497472, 113246208)   cvt out NHWC bf16 [8][HW][64] (dies after conv1)
//   H1 [113246208, 150994944)  conv1 out NHWC bf16 (dies after conv2)
//   X  [75497472, 214958080)   concat NCHW bf16 [4][473][HW] (overlays X1+H1)
//   weights at 215322624 (~260 KB)
extern "C" void kernel_launch(void* const* d_in, const int* in_sizes, int n_in,
                              void* d_out, int out_size, void* d_ws, size_t ws_size,
                              hipStream_t stream){
  char* ws = (char*)d_ws;
  u16* C2 = (u16*)ws;
  u16* X1 = (u16*)(ws + 75497472);
  u16* H1 = (u16*)(ws + 113246208);
  u16* X  = (u16*)(ws + 75497472);
  u16* w1m = (u16*)(ws + 215322624);
  u16* w2m = w1m + 36864;
  float* wrf = (float*)(w2m + 73728);
  unsigned int* wpb = (unsigned int*)(wrf + 4096);
  float* b1f = (float*)(wpb + 4266);
  float* b2f = b1f + 64;
  float* rbf = b2f + 128;
  int* flag  = (int*)(rbf + 32);

  detect_k<<<1,256,0,stream>>>((const unsigned int*)d_in[0], flag);
  cvt_t<<<dim3(576,8),256,0,stream>>>(d_in[0], d_in[1], X1, flag);
  prep_w<<<288,256,0,stream>>>(d_in[2], d_in[4], d_in[6], d_in[8],
                               d_in[3], d_in[5], d_in[7],
                               w1m, w2m, wrf, wpb, b1f, b2f, rbf, flag);
  conv_mfma<1><<<dim3(6,48,8),128,0,stream>>>(X1, w1m, b1f, H1);
  conv_mfma<2><<<dim3(6,48,8),256,0,stream>>>(H1, w2m, b2f, C2);
  redir_k<<<576,256,0,stream>>>(C2, wrf, rbf, X);
  zero_k<<<dim3(40,4),256,0,stream>>>(X);
  corr_k<<<dim3(768),256,0,stream>>>(C2, X);
  final_k<<<dim3(192,4),192,0,stream>>>(X, wpb, d_out, flag);
}

// Round 5
// 602.664 us; speedup vs baseline: 1.5216x; 1.0387x over previous
//
#include <hip/hip_runtime.h>
#include <hip/hip_bf16.h>

#define HH 192
#define WW 192
#define HW (HH*WW)

typedef unsigned short u16;
typedef __attribute__((ext_vector_type(8))) short short8;
typedef __attribute__((ext_vector_type(16))) float float16;
typedef __attribute__((ext_vector_type(4))) float f32x4;

__device__ __forceinline__ float b2f(u16 u){
  union { unsigned int i; float f; } v; v.i = ((unsigned int)u) << 16; return v.f;
}
__device__ __forceinline__ u16 f2b(float f){
  union { unsigned int i; float f; } v; v.f = f;
  unsigned int r = v.i + 0x7FFFu + ((v.i >> 16) & 1u);
  return (u16)(r >> 16);
}
__device__ __forceinline__ void up2(unsigned int w, float& lo, float& hi){
  union { unsigned int i; float f; } a, b;
  a.i = w << 16; b.i = w & 0xFFFF0000u;
  lo = a.f; hi = b.f;
}
__device__ __forceinline__ float lrelu(float x){ return x >= 0.f ? x : 0.1f*x; }
__device__ __forceinline__ float ldmix(const void* p, int i, bool bf){
  return bf ? b2f(((const u16*)p)[i]) : ((const float*)p)[i];
}

using bf2 = __attribute__((ext_vector_type(2))) __bf16;
__device__ __forceinline__ float dot2bf(unsigned int a, unsigned int b, float c){
#if __has_builtin(__builtin_amdgcn_fdot2_f32_bf16)
  union { unsigned int u; bf2 v; } ua, ub; ua.u = a; ub.u = b;
  return __builtin_amdgcn_fdot2_f32_bf16(ua.v, ub.v, c, false);
#else
  float al,ah,bl,bh; up2(a,al,ah); up2(b,bl,bh);
  return c + al*bl + ah*bh;
#endif
}

union AU { uint4 q; short8 s; };
__device__ __forceinline__ short8 s8(const uint4& q){ AU u; u.q = q; return u.s; }

__global__ __launch_bounds__(256) void detect_k(const unsigned int* __restrict__ w, int* __restrict__ flag){
  __shared__ int cnt;
  if (threadIdx.x == 0) cnt = 0;
  __syncthreads();
  unsigned int v = w[(size_t)threadIdx.x * 1024];
  int e = (v >> 7) & 0xFF;
  bool ok = ((v & 0xFFFFu) == 0u) || (e > 100 && e < 150);
  if (ok) atomicAdd(&cnt, 1);
  __syncthreads();
  if (threadIdx.x == 0) *flag = (cnt >= 192) ? 1 : 0;
}

// NCHW (fp32 or bf16) -> NHWC bf16 [8][HW][64] via LDS transpose tile.
__global__ __launch_bounds__(256) void cvt_t(const void* __restrict__ pred, const void* __restrict__ refp,
                                             u16* __restrict__ X1, const int* __restrict__ flag){
  __shared__ u16 t[64*72];
  int tid = threadIdx.x;
  int px0 = blockIdx.x*64, img = blockIdx.y;
  bool bf = (*flag != 0);
  const void* src = (img < 4) ? pred : refp;
  int im = (img < 4) ? img : img - 4;
  for (int e = tid; e < 4096; e += 256){
    int ch = e >> 6, px = e & 63;
    t[px*72 + ch] = f2b(ldmix(src, (im*64 + ch)*HW + px0 + px, bf));
  }
  __syncthreads();
  int px = tid >> 2, q = tid & 3;
  uint4 v0 = *(const uint4*)(t + px*72 + q*16);
  uint4 v1 = *(const uint4*)(t + px*72 + q*16 + 8);
  u16* dst = X1 + ((size_t)img*HW + px0 + px)*64 + q*16;
  *(uint4*)dst = v0;
  *(uint4*)(dst + 8) = v1;
}

// Weight prep.
__global__ __launch_bounds__(256) void prep_w(const void* __restrict__ w1, const void* __restrict__ w2,
                                              const void* __restrict__ wr, const void* __restrict__ wp,
                                              const void* __restrict__ b1, const void* __restrict__ b2,
                                              const void* __restrict__ rb,
                                              u16* __restrict__ w1m, u16* __restrict__ w2m,
                                              float* __restrict__ wrf, unsigned int* __restrict__ wpb,
                                              float* __restrict__ b1f, float* __restrict__ b2f,
                                              float* __restrict__ rbf, const int* __restrict__ flag){
  int i = blockIdx.x*256 + threadIdx.x;
  bool bf = (*flag != 0);
  if (i < 36864){
    int j = i & 7, lane = (i>>3) & 63, cot = (i>>9) & 1, ks = (i>>10) & 3, tap = i >> 12;
    int co = cot*32 + (lane & 31), ci = ks*16 + (lane>>5)*8 + j;
    w1m[i] = f2b(ldmix(w1, (co*64 + ci)*9 + tap, bf));
  }
  if (i < 73728){
    int j = i & 7, lane = (i>>3) & 63, cot = (i>>9) & 3, ks = (i>>11) & 3, tap = i >> 13;
    int co = cot*32 + (lane & 31), ci = ks*16 + (lane>>5)*8 + j;
    w2m[i] = f2b(ldmix(w2, (co*64 + ci)*9 + tap, bf));
  }
  if (i < 4096){ int co = i & 31; int ci = i >> 5;
    wrf[ci*32+co] = ldmix(wr, co*128+ci, bf); }
  if (i < 4266){
    int cp = i/18; int rr = i - cp*18; int tap = rr >> 1; int o = rr & 1;
    int c0 = 2*cp, c1 = c0 + 1;
    float f0 = ldmix(wp, (o*473+c0)*9+tap, bf);
    float f1 = (c1 < 473) ? ldmix(wp, (o*473+c1)*9+tap, bf) : 0.f;
    wpb[i] = (unsigned int)f2b(f0) | ((unsigned int)f2b(f1) << 16);
  }
  if (i < 64)  b1f[i] = ldmix(b1, i, bf);
  if (i < 128) b2f[i] = ldmix(b2, i, bf);
  if (i < 32)  rbf[i] = ldmix(rb, i, bf);
}

// MFMA implicit-GEMM 3x3 conv, pad=1, NHWC bf16 in/out, bias+lrelu.
template<int WCO>
__global__ __launch_bounds__(WCO*128) void conv_mfma(const u16* __restrict__ in, const u16* __restrict__ wm,
                                                     const float* __restrict__ bias, u16* __restrict__ out){
  constexpr int COUT = WCO*64;
  constexpr int NCOT = WCO*2;
  constexpr int THREADS = WCO*128;
  constexpr int CO_PAD = COUT + 8;
  constexpr int SLAB = 6*34*72;            // 14688 u16
  constexpr int OT   = 128*CO_PAD;
  __shared__ __align__(16) u16 smem[(SLAB > OT) ? SLAB : OT];

  int tid = threadIdx.x, lane = tid & 63, w = tid >> 6;
  int wr = w & 1, wc = w >> 1;
  int n = lane & 31, kh = lane >> 5;
  int x0 = blockIdx.x*32, y0 = blockIdx.y*4, img = blockIdx.z;
  const u16* inb = in + (size_t)img*HW*64;

  float16 acc[2][2];
  #pragma unroll
  for (int t=0;t<2;t++)
    #pragma unroll
    for (int c=0;c<2;c++)
      #pragma unroll
      for (int k=0;k<16;k++) acc[t][c][k] = 0.f;

  for (int e = tid; e < 1632; e += THREADS){
    int c8 = e & 7; int pp = e >> 3;
    int row = pp / 34, pos = pp - row*34;
    int gy = y0 + row - 1, gx = x0 + pos - 1;
    uint4 v = make_uint4(0,0,0,0);
    if (gy >= 0 && gy < HH && gx >= 0 && gx < WW)
      v = *(const uint4*)(inb + ((size_t)gy*WW + gx)*64 + c8*8);
    *(uint4*)(smem + pp*72 + c8*8) = v;
  }
  __syncthreads();

  union BU { uint2 u[2]; short8 s; };

  #pragma unroll 1
  for (int ky = 0; ky < 3; ++ky){
    #pragma unroll 1
    for (int kx = 0; kx < 3; ++kx){
      int tap = ky*3 + kx;
      #pragma unroll
      for (int ks = 0; ks < 4; ++ks){
        AU a0, a1;
        const u16* wmp = wm + (((size_t)(tap*4 + ks)*NCOT + wc*2)*64 + lane)*8;
        a0.q = *(const uint4*)(wmp);
        a1.q = *(const uint4*)(wmp + 512);
        #pragma unroll
        for (int t = 0; t < 2; ++t){
          int row = wr*2 + t + ky;
          int off = (row*34 + n + kx)*72 + ks*16 + kh*8;
          BU b;
          b.u[0] = *(const uint2*)(smem + off);
          b.u[1] = *(const uint2*)(smem + off + 4);
          acc[t][0] = __builtin_amdgcn_mfma_f32_32x32x16_bf16(a0.s, b.s, acc[t][0], 0, 0, 0);
          acc[t][1] = __builtin_amdgcn_mfma_f32_32x32x16_bf16(a1.s, b.s, acc[t][1], 0, 0, 0);
        }
      }
    }
  }

  __syncthreads();
  #pragma unroll
  for (int t = 0; t < 2; ++t){
    int pxl = (wr*2 + t)*32 + n;
    #pragma unroll
    for (int c = 0; c < 2; ++c){
      int cob = wc*64 + c*32 + 4*kh;
      #pragma unroll
      for (int p = 0; p < 8; ++p){
        int co = cob + (p&1)*2 + (p>>1)*8;
        float2 bb = *(const float2*)(bias + co);
        float v0 = lrelu(acc[t][c][2*p]   + bb.x);
        float v1 = lrelu(acc[t][c][2*p+1] + bb.y);
        unsigned int pk = (unsigned int)f2b(v0) | ((unsigned int)f2b(v1) << 16);
        *(unsigned int*)(smem + pxl*CO_PAD + co) = pk;
      }
    }
  }
  __syncthreads();
  int px, part;
  if (WCO == 2){ px = tid >> 1; part = tid & 1; } else { px = tid; part = 0; }
  const u16* sp = smem + px*CO_PAD + part*64;
  u16* gp = out + ((size_t)img*HW + (size_t)(y0 + (px>>5))*WW + x0 + (px&31))*COUT + part*64;
  #pragma unroll
  for (int k = 0; k < 8; ++k)
    *(uint4*)(gp + k*8) = *(const uint4*)(sp + k*8);
}

// 1x1 redir conv (128->32) + bias + lrelu. X NCHW [b][473][HW]; planes 0..31.
__global__ __launch_bounds__(256) void redir_k(const u16* __restrict__ C2, const float* __restrict__ wrf,
                                               const float* __restrict__ rbf, u16* __restrict__ X){
  int p = blockIdx.x*256 + threadIdx.x;
  int b = p / HW; int pix = p - b*HW;
  const u16* ap = C2 + (size_t)p*128;
  float acc[32];
  #pragma unroll
  for (int j=0;j<32;j++) acc[j]=0.f;
  for (int ci=0; ci<128; ci+=4){
    uint2 aw = *(const uint2*)(ap + ci);
    float a0,a1,a2,a3;
    up2(aw.x,a0,a1); up2(aw.y,a2,a3);
    const float* w0 = wrf + ci*32;
    #pragma unroll
    for (int co=0; co<32; co+=4){
      float4 wv0 = *(const float4*)(w0+co);
      float4 wv1 = *(const float4*)(w0+32+co);
      float4 wv2 = *(const float4*)(w0+64+co);
      float4 wv3 = *(const float4*)(w0+96+co);
      acc[co+0] += a0*wv0.x + a1*wv1.x + a2*wv2.x + a3*wv3.x;
      acc[co+1] += a0*wv0.y + a1*wv1.y + a2*wv2.y + a3*wv3.y;
      acc[co+2] += a0*wv0.z + a1*wv1.z + a2*wv2.z + a3*wv3.z;
      acc[co+3] += a0*wv0.w + a1*wv1.w + a2*wv2.w + a3*wv3.w;
    }
  }
  #pragma unroll
  for (int co=0; co<32; ++co){
    X[(size_t)(b*473 + co)*HW + pix] = f2b(lrelu(acc[co] + rbf[co]));
  }
}

// Zero the orphan (y,dy) plane rows (r = y+2dy-20 outside [0,192)).
__global__ __launch_bounds__(256) void zero_k(u16* __restrict__ X){
  int yi = blockIdx.x, b = blockIdx.y;
  int y = (yi < 20) ? yi : 152 + yi;           // y in [0,20) or [172,192)
  int locnt = (yi < 20) ? ((21 - y) >> 1) : 0; // orphan dy = 0..locnt-1
  int hi0 = (213 - y) >> 1;                    // first orphan dy at high end
  int hicnt = (yi < 20) ? 0 : (21 - hi0);
  int ncnt = locnt + hicnt;
  u16* Xb = X + ((size_t)(b*473 + 32))*HW + (size_t)y*WW;
  int total = ncnt*2016;
  for (int e = threadIdx.x; e < total; e += 256){
    int i = e / 2016, rem = e - i*2016;
    int dy = (i < locnt) ? i : (hi0 + i - locnt);
    int d = rem / 96, xw = rem - d*96;
    *(unsigned int*)(Xb + ((size_t)(dy*21 + d))*HW + 2*xw) = 0u;
  }
}

// ---------------------------------------------------------------------------
// Correlation, round 10: B-row-centric, parity-packed 16x16x32 MFMA, no LDS
// staging (see round 3 notes).
// ---------------------------------------------------------------------------
__global__ __launch_bounds__(256,2) void corr_k(const u16* __restrict__ C2, u16* __restrict__ X){
  __shared__ __align__(16) u16 smE[4160];

  int bid = blockIdx.x;
  int v = (bid & 7)*96 + (bid >> 3);       // XCD-contiguous, bijective (768 = 8*96)
  int b = v / 192, r = v - b*192;

  int tid = threadIdx.x, lane = tid & 63, w = tid >> 6;
  int n = lane & 15, s = lane >> 4;
  int p = w & 1, u0w = (w >> 1)*48;

  const u16* Brow = C2 + ((size_t)(b+4)*HW + (size_t)r*WW)*128;
  const u16* Aimg = C2 + (size_t)b*HW*128;

  uint4 bf[4][5];
  #pragma unroll
  for (int l = 0; l < 5; ++l){
    int zq = u0w + 16*l + n - 16;
    bool vz = ((unsigned)zq < 96u);
    const u16* bp = Brow + (long)(2*zq + p)*128;
    #pragma unroll
    for (int kk = 0; kk < 4; ++kk){
      uint4 t0 = make_uint4(0,0,0,0);
      if (vz) t0 = *(const uint4*)(bp + (kk*4 + s)*8);
      bf[kk][l] = t0;
    }
  }

  int dylo = max(0, (r-170)>>1);
  int dyhi = min(20, (r+20)>>1);

  uint4 A[3][4];
  f32x4 acc[3][3];

  auto loadA = [&](int yy){
    const u16* Ay = Aimg + (size_t)yy*WW*128;
    #pragma unroll
    for (int t = 0; t < 3; ++t){
      const u16* apx = Ay + (size_t)(2*(u0w + 16*t + n) + p)*128;
      #pragma unroll
      for (int kk = 0; kk < 4; ++kk)
        A[t][kk] = *(const uint4*)(apx + (kk*4 + s)*8);
    }
  };

  int nm6 = n - 4*s - 6;
  auto eout = [&](int yy, int dyy){
    #pragma unroll
    for (int t = 0; t < 3; ++t){
      int xb2 = 2*(u0w + 16*t) + p + 8*s;
      #pragma unroll
      for (int j = 0; j < 3; ++j){
        #pragma unroll
        for (int q = 0; q < 4; ++q){
          int dd = nm6 - q + 16*j;
          if ((unsigned)dd <= 20u){
            float val = acc[t][j][q]*(1.f/128.f);
            val = fmaxf(val, 0.f) + 0.1f*fminf(val, 0.f);
            smE[dd*198 + xb2 + 2*q] = f2b(val);
          }
        }
      }
    }
    __syncthreads();
    u16* Xp = X + ((size_t)(b*473 + 32 + dyy*21))*HW + (size_t)yy*WW;
    #pragma unroll
    for (int e0 = 0; e0 < 8; ++e0){
      int e = e0*256 + tid;
      if (e < 2016){
        int d = e/96, xw = e - d*96;
        *(unsigned int*)(Xp + (size_t)d*HW + 2*xw) = *(const unsigned int*)(smE + d*198 + 2*xw);
      }
    }
    __syncthreads();
  };

  loadA(r + 20 - 2*dylo);

  #pragma unroll 1
  for (int dy = dylo; dy <= dyhi; ++dy){
    int y = r + 20 - 2*dy;
    if (dy > dylo) eout(y + 2, dy - 1);
    #pragma unroll
    for (int t = 0; t < 3; ++t)
      #pragma unroll
      for (int j = 0; j < 3; ++j)
        acc[t][j] = (f32x4){0.f, 0.f, 0.f, 0.f};
    #pragma unroll
    for (int kk = 0; kk < 4; ++kk)
      #pragma unroll
      for (int t = 0; t < 3; ++t)
        #pragma unroll
        for (int j = 0; j < 3; ++j)
          acc[t][j] = __builtin_amdgcn_mfma_f32_16x16x32_bf16(
              s8(A[t][kk]), s8(bf[kk][t+j]), acc[t][j], 0, 0, 0);
    if (dy < dyhi) loadA(y - 2);
  }
  eout(r + 20 - 2*dyhi, dyhi);
}

// Final 3x3 conv: contribution-passing, round 11: cp-loop unrolled x4 with
// batched loads (24 in flight) to break the 2-deep latency chain (VGPR was
// 12 -> no MLP; 215us latency-bound with all pipes <13%).
__global__ __launch_bounds__(192) void final_k(const u16* __restrict__ X, const unsigned int* __restrict__ wpb,
                                               void* __restrict__ out, const int* __restrict__ flag){
  __shared__ float eR[4][2], eL[4][2];
  int x = threadIdx.x, y = blockIdx.x, b = blockIdx.y;
  int w = x >> 6, lane = x & 63;
  const u16* Xb = X + (size_t)b*473*HW;
  float Pm0=0.f,Pm1=0.f,Pl0=0.f,Pl1=0.f,Pr0=0.f,Pr1=0.f;
  bool rok0 = (y > 0), rok2 = (y < HH-1);
  size_t off0 = (size_t)(y-1)*WW + x;
  size_t off1 = (size_t)(y  )*WW + x;
  size_t off2 = (size_t)(y+1)*WW + x;

  #pragma unroll 1
  for (int it = 0; it < 59; ++it){
    int cp0 = it*4;
    unsigned int vv[4][3];
    #pragma unroll
    for (int u = 0; u < 4; ++u){
      size_t base0 = (size_t)(2*(cp0+u))*HW;
      size_t base1 = base0 + HW;
      #pragma unroll
      for (int r = 0; r < 3; ++r){
        bool ok = (r==0) ? rok0 : ((r==2) ? rok2 : true);
        size_t off = (r==0) ? off0 : ((r==2) ? off2 : off1);
        unsigned int lo = 0, hi = 0;
        if (ok){
          lo = Xb[base0 + off];
          hi = Xb[base1 + off];
        }
        vv[u][r] = lo | (hi << 16);
      }
    }
    #pragma unroll
    for (int u = 0; u < 4; ++u){
      const unsigned int* w18 = wpb + (cp0+u)*18;
      #pragma unroll
      for (int r = 0; r < 3; ++r){
        unsigned int v = vv[u][r];
        Pm0 = dot2bf(v, w18[(r*3+1)*2+0], Pm0);
        Pm1 = dot2bf(v, w18[(r*3+1)*2+1], Pm1);
        Pl0 = dot2bf(v, w18[(r*3+2)*2+0], Pl0);
        Pl1 = dot2bf(v, w18[(r*3+2)*2+1], Pl1);
        Pr0 = dot2bf(v, w18[(r*3+0)*2+0], Pr0);
        Pr1 = dot2bf(v, w18[(r*3+0)*2+1], Pr1);
      }
    }
  }
  { // tail pair cp=236 (c0=472, c1 OOB -> weight hi already 0; load lo only)
    const unsigned int* w18 = wpb + 236*18;
    size_t base0 = (size_t)472*HW;
    unsigned int vv[3];
    #pragma unroll
    for (int r = 0; r < 3; ++r){
      bool ok = (r==0) ? rok0 : ((r==2) ? rok2 : true);
      size_t off = (r==0) ? off0 : ((r==2) ? off2 : off1);
      vv[r] = ok ? (unsigned int)Xb[base0 + off] : 0u;
    }
    #pragma unroll
    for (int r = 0; r < 3; ++r){
      unsigned int v = vv[r];
      Pm0 = dot2bf(v, w18[(r*3+1)*2+0], Pm0);
      Pm1 = dot2bf(v, w18[(r*3+1)*2+1], Pm1);
      Pl0 = dot2bf(v, w18[(r*3+2)*2+0], Pl0);
      Pl1 = dot2bf(v, w18[(r*3+2)*2+1], Pl1);
      Pr0 = dot2bf(v, w18[(r*3+0)*2+0], Pr0);
      Pr1 = dot2bf(v, w18[(r*3+0)*2+1], Pr1);
    }
  }

  float r0 = __shfl_up(Pr0,1), r1 = __shfl_up(Pr1,1);
  float l0 = __shfl_down(Pl0,1), l1 = __shfl_down(Pl1,1);
  if (x == 0){ eR[0][0]=0.f; eR[0][1]=0.f; eL[3][0]=0.f; eL[3][1]=0.f; }
  if (lane == 63){ eR[w+1][0]=Pr0; eR[w+1][1]=Pr1; }
  if (lane == 0 && w > 0){ eL[w][0]=Pl0; eL[w][1]=Pl1; }
  __syncthreads();
  if (lane == 0){ r0 = eR[w][0]; r1 = eR[w][1]; }
  if (lane == 63){ l0 = eL[w+1][0]; l1 = eL[w+1][1]; }
  float a0 = Pm0 + r0 + l0;
  float a1 = Pm1 + r1 + l1;

  size_t rem = (size_t)y*WW + x;
  size_t i0 = (size_t)(b*2)*HW + rem;
  size_t i1 = (size_t)(b*2+1)*HW + rem;
  if (*flag){
    ((u16*)out)[i0] = f2b(a0);
    ((u16*)out)[i1] = f2b(a1);
  } else {
    ((float*)out)[i0] = a0;
    ((float*)out)[i1] = a1;
  }
}

// Workspace (bytes):
//   C2 [0, 75497472)           conv2 out NHWC bf16 [8][HW][128]
//   X1 [75497472, 113246208)   cvt out NHWC bf16 [8][HW][64] (dies after conv1)
//   H1 [113246208, 150994944)  conv1 out NHWC bf16 (dies after conv2)
//   X  [75497472, 214958080)   concat NCHW bf16 [4][473][HW] (overlays X1+H1)
//   weights at 215322624 (~260 KB)
extern "C" void kernel_launch(void* const* d_in, const int* in_sizes, int n_in,
                              void* d_out, int out_size, void* d_ws, size_t ws_size,
                              hipStream_t stream){
  char* ws = (char*)d_ws;
  u16* C2 = (u16*)ws;
  u16* X1 = (u16*)(ws + 75497472);
  u16* H1 = (u16*)(ws + 113246208);
  u16* X  = (u16*)(ws + 75497472);
  u16* w1m = (u16*)(ws + 215322624);
  u16* w2m = w1m + 36864;
  float* wrf = (float*)(w2m + 73728);
  unsigned int* wpb = (unsigned int*)(wrf + 4096);
  float* b1f = (float*)(wpb + 4266);
  float* b2f = b1f + 64;
  float* rbf = b2f + 128;
  int* flag  = (int*)(rbf + 32);

  detect_k<<<1,256,0,stream>>>((const unsigned int*)d_in[0], flag);
  cvt_t<<<dim3(576,8),256,0,stream>>>(d_in[0], d_in[1], X1, flag);
  prep_w<<<288,256,0,stream>>>(d_in[2], d_in[4], d_in[6], d_in[8],
                               d_in[3], d_in[5], d_in[7],
                               w1m, w2m, wrf, wpb, b1f, b2f, rbf, flag);
  conv_mfma<1><<<dim3(6,48,8),128,0,stream>>>(X1, w1m, b1f, H1);
  conv_mfma<2><<<dim3(6,48,8),256,0,stream>>>(H1, w2m, b2f, C2);
  redir_k<<<576,256,0,stream>>>(C2, wrf, rbf, X);
  zero_k<<<dim3(40,4),256,0,stream>>>(X);
  corr_k<<<dim3(768),256,0,stream>>>(C2, X);
  final_k<<<dim3(192,4),192,0,stream>>>(X, wpb, d_out, flag);
}

// Round 6
// 512.166 us; speedup vs baseline: 1.7905x; 1.1767x over previous
//
#include <hip/hip_runtime.h>
#include <hip/hip_bf16.h>

#define HH 192
#define WW 192
#define HW (HH*WW)

typedef unsigned short u16;
typedef __attribute__((ext_vector_type(8))) short short8;
typedef __attribute__((ext_vector_type(16))) float float16;
typedef __attribute__((ext_vector_type(4))) float f32x4;

__device__ __forceinline__ float b2f(u16 u){
  union { unsigned int i; float f; } v; v.i = ((unsigned int)u) << 16; return v.f;
}
__device__ __forceinline__ u16 f2b(float f){
  union { unsigned int i; float f; } v; v.f = f;
  unsigned int r = v.i + 0x7FFFu + ((v.i >> 16) & 1u);
  return (u16)(r >> 16);
}
__device__ __forceinline__ void up2(unsigned int w, float& lo, float& hi){
  union { unsigned int i; float f; } a, b;
  a.i = w << 16; b.i = w & 0xFFFF0000u;
  lo = a.f; hi = b.f;
}
__device__ __forceinline__ float lrelu(float x){ return x >= 0.f ? x : 0.1f*x; }
__device__ __forceinline__ float ldmix(const void* p, int i, bool bf){
  return bf ? b2f(((const u16*)p)[i]) : ((const float*)p)[i];
}

using bf2 = __attribute__((ext_vector_type(2))) __bf16;
__device__ __forceinline__ float dot2bf(unsigned int a, unsigned int b, float c){
#if __has_builtin(__builtin_amdgcn_fdot2_f32_bf16)
  union { unsigned int u; bf2 v; } ua, ub; ua.u = a; ub.u = b;
  return __builtin_amdgcn_fdot2_f32_bf16(ua.v, ub.v, c, false);
#else
  float al,ah,bl,bh; up2(a,al,ah); up2(b,bl,bh);
  return c + al*bl + ah*bh;
#endif
}

union AU { uint4 q; short8 s; };
__device__ __forceinline__ short8 s8(const uint4& q){ AU u; u.q = q; return u.s; }

__global__ __launch_bounds__(256) void detect_k(const unsigned int* __restrict__ w, int* __restrict__ flag){
  __shared__ int cnt;
  if (threadIdx.x == 0) cnt = 0;
  __syncthreads();
  unsigned int v = w[(size_t)threadIdx.x * 1024];
  int e = (v >> 7) & 0xFF;
  bool ok = ((v & 0xFFFFu) == 0u) || (e > 100 && e < 150);
  if (ok) atomicAdd(&cnt, 1);
  __syncthreads();
  if (threadIdx.x == 0) *flag = (cnt >= 192) ? 1 : 0;
}

// NCHW (fp32 or bf16) -> NHWC bf16 [8][HW][64] via LDS transpose tile.
__global__ __launch_bounds__(256) void cvt_t(const void* __restrict__ pred, const void* __restrict__ refp,
                                             u16* __restrict__ X1, const int* __restrict__ flag){
  __shared__ u16 t[64*72];
  int tid = threadIdx.x;
  int px0 = blockIdx.x*64, img = blockIdx.y;
  bool bf = (*flag != 0);
  const void* src = (img < 4) ? pred : refp;
  int im = (img < 4) ? img : img - 4;
  for (int e = tid; e < 4096; e += 256){
    int ch = e >> 6, px = e & 63;
    t[px*72 + ch] = f2b(ldmix(src, (im*64 + ch)*HW + px0 + px, bf));
  }
  __syncthreads();
  int px = tid >> 2, q = tid & 3;
  uint4 v0 = *(const uint4*)(t + px*72 + q*16);
  uint4 v1 = *(const uint4*)(t + px*72 + q*16 + 8);
  u16* dst = X1 + ((size_t)img*HW + px0 + px)*64 + q*16;
  *(uint4*)dst = v0;
  *(uint4*)(dst + 8) = v1;
}

// Weight prep.
__global__ __launch_bounds__(256) void prep_w(const void* __restrict__ w1, const void* __restrict__ w2,
                                              const void* __restrict__ wr, const void* __restrict__ wp,
                                              const void* __restrict__ b1, const void* __restrict__ b2,
                                              const void* __restrict__ rb,
                                              u16* __restrict__ w1m, u16* __restrict__ w2m,
                                              float* __restrict__ wrf, unsigned int* __restrict__ wpb,
                                              float* __restrict__ b1f, float* __restrict__ b2f,
                                              float* __restrict__ rbf, const int* __restrict__ flag){
  int i = blockIdx.x*256 + threadIdx.x;
  bool bf = (*flag != 0);
  if (i < 36864){
    int j = i & 7, lane = (i>>3) & 63, cot = (i>>9) & 1, ks = (i>>10) & 3, tap = i >> 12;
    int co = cot*32 + (lane & 31), ci = ks*16 + (lane>>5)*8 + j;
    w1m[i] = f2b(ldmix(w1, (co*64 + ci)*9 + tap, bf));
  }
  if (i < 73728){
    int j = i & 7, lane = (i>>3) & 63, cot = (i>>9) & 3, ks = (i>>11) & 3, tap = i >> 13;
    int co = cot*32 + (lane & 31), ci = ks*16 + (lane>>5)*8 + j;
    w2m[i] = f2b(ldmix(w2, (co*64 + ci)*9 + tap, bf));
  }
  if (i < 4096){ int co = i & 31; int ci = i >> 5;
    wrf[ci*32+co] = ldmix(wr, co*128+ci, bf); }
  if (i < 4266){
    int cp = i/18; int rr = i - cp*18; int tap = rr >> 1; int o = rr & 1;
    int c0 = 2*cp, c1 = c0 + 1;
    float f0 = ldmix(wp, (o*473+c0)*9+tap, bf);
    float f1 = (c1 < 473) ? ldmix(wp, (o*473+c1)*9+tap, bf) : 0.f;
    wpb[i] = (unsigned int)f2b(f0) | ((unsigned int)f2b(f1) << 16);
  }
  if (i < 64)  b1f[i] = ldmix(b1, i, bf);
  if (i < 128) b2f[i] = ldmix(b2, i, bf);
  if (i < 32)  rbf[i] = ldmix(rb, i, bf);
}

// MFMA implicit-GEMM 3x3 conv, pad=1, NHWC bf16 in/out, bias+lrelu.
template<int WCO>
__global__ __launch_bounds__(WCO*128) void conv_mfma(const u16* __restrict__ in, const u16* __restrict__ wm,
                                                     const float* __restrict__ bias, u16* __restrict__ out){
  constexpr int COUT = WCO*64;
  constexpr int NCOT = WCO*2;
  constexpr int THREADS = WCO*128;
  constexpr int CO_PAD = COUT + 8;
  constexpr int SLAB = 6*34*72;            // 14688 u16
  constexpr int OT   = 128*CO_PAD;
  __shared__ __align__(16) u16 smem[(SLAB > OT) ? SLAB : OT];

  int tid = threadIdx.x, lane = tid & 63, w = tid >> 6;
  int wr = w & 1, wc = w >> 1;
  int n = lane & 31, kh = lane >> 5;
  int x0 = blockIdx.x*32, y0 = blockIdx.y*4, img = blockIdx.z;
  const u16* inb = in + (size_t)img*HW*64;

  float16 acc[2][2];
  #pragma unroll
  for (int t=0;t<2;t++)
    #pragma unroll
    for (int c=0;c<2;c++)
      #pragma unroll
      for (int k=0;k<16;k++) acc[t][c][k] = 0.f;

  for (int e = tid; e < 1632; e += THREADS){
    int c8 = e & 7; int pp = e >> 3;
    int row = pp / 34, pos = pp - row*34;
    int gy = y0 + row - 1, gx = x0 + pos - 1;
    uint4 v = make_uint4(0,0,0,0);
    if (gy >= 0 && gy < HH && gx >= 0 && gx < WW)
      v = *(const uint4*)(inb + ((size_t)gy*WW + gx)*64 + c8*8);
    *(uint4*)(smem + pp*72 + c8*8) = v;
  }
  __syncthreads();

  union BU { uint2 u[2]; short8 s; };

  #pragma unroll 1
  for (int ky = 0; ky < 3; ++ky){
    #pragma unroll 1
    for (int kx = 0; kx < 3; ++kx){
      int tap = ky*3 + kx;
      #pragma unroll
      for (int ks = 0; ks < 4; ++ks){
        AU a0, a1;
        const u16* wmp = wm + (((size_t)(tap*4 + ks)*NCOT + wc*2)*64 + lane)*8;
        a0.q = *(const uint4*)(wmp);
        a1.q = *(const uint4*)(wmp + 512);
        #pragma unroll
        for (int t = 0; t < 2; ++t){
          int row = wr*2 + t + ky;
          int off = (row*34 + n + kx)*72 + ks*16 + kh*8;
          BU b;
          b.u[0] = *(const uint2*)(smem + off);
          b.u[1] = *(const uint2*)(smem + off + 4);
          acc[t][0] = __builtin_amdgcn_mfma_f32_32x32x16_bf16(a0.s, b.s, acc[t][0], 0, 0, 0);
          acc[t][1] = __builtin_amdgcn_mfma_f32_32x32x16_bf16(a1.s, b.s, acc[t][1], 0, 0, 0);
        }
      }
    }
  }

  __syncthreads();
  #pragma unroll
  for (int t = 0; t < 2; ++t){
    int pxl = (wr*2 + t)*32 + n;
    #pragma unroll
    for (int c = 0; c < 2; ++c){
      int cob = wc*64 + c*32 + 4*kh;
      #pragma unroll
      for (int p = 0; p < 8; ++p){
        int co = cob + (p&1)*2 + (p>>1)*8;
        float2 bb = *(const float2*)(bias + co);
        float v0 = lrelu(acc[t][c][2*p]   + bb.x);
        float v1 = lrelu(acc[t][c][2*p+1] + bb.y);
        unsigned int pk = (unsigned int)f2b(v0) | ((unsigned int)f2b(v1) << 16);
        *(unsigned int*)(smem + pxl*CO_PAD + co) = pk;
      }
    }
  }
  __syncthreads();
  int px, part;
  if (WCO == 2){ px = tid >> 1; part = tid & 1; } else { px = tid; part = 0; }
  const u16* sp = smem + px*CO_PAD + part*64;
  u16* gp = out + ((size_t)img*HW + (size_t)(y0 + (px>>5))*WW + x0 + (px&31))*COUT + part*64;
  #pragma unroll
  for (int k = 0; k < 8; ++k)
    *(uint4*)(gp + k*8) = *(const uint4*)(sp + k*8);
}

// 1x1 redir conv (128->32) + bias + lrelu. X NCHW [b][473][HW]; planes 0..31.
__global__ __launch_bounds__(256) void redir_k(const u16* __restrict__ C2, const float* __restrict__ wrf,
                                               const float* __restrict__ rbf, u16* __restrict__ X){
  int p = blockIdx.x*256 + threadIdx.x;
  int b = p / HW; int pix = p - b*HW;
  const u16* ap = C2 + (size_t)p*128;
  float acc[32];
  #pragma unroll
  for (int j=0;j<32;j++) acc[j]=0.f;
  for (int ci=0; ci<128; ci+=4){
    uint2 aw = *(const uint2*)(ap + ci);
    float a0,a1,a2,a3;
    up2(aw.x,a0,a1); up2(aw.y,a2,a3);
    const float* w0 = wrf + ci*32;
    #pragma unroll
    for (int co=0; co<32; co+=4){
      float4 wv0 = *(const float4*)(w0+co);
      float4 wv1 = *(const float4*)(w0+32+co);
      float4 wv2 = *(const float4*)(w0+64+co);
      float4 wv3 = *(const float4*)(w0+96+co);
      acc[co+0] += a0*wv0.x + a1*wv1.x + a2*wv2.x + a3*wv3.x;
      acc[co+1] += a0*wv0.y + a1*wv1.y + a2*wv2.y + a3*wv3.y;
      acc[co+2] += a0*wv0.z + a1*wv1.z + a2*wv2.z + a3*wv3.z;
      acc[co+3] += a0*wv0.w + a1*wv1.w + a2*wv2.w + a3*wv3.w;
    }
  }
  #pragma unroll
  for (int co=0; co<32; ++co){
    X[(size_t)(b*473 + co)*HW + pix] = f2b(lrelu(acc[co] + rbf[co]));
  }
}

// Zero the orphan (y,dy) plane rows (r = y+2dy-20 outside [0,192)).
__global__ __launch_bounds__(256) void zero_k(u16* __restrict__ X){
  int yi = blockIdx.x, b = blockIdx.y;
  int y = (yi < 20) ? yi : 152 + yi;           // y in [0,20) or [172,192)
  int locnt = (yi < 20) ? ((21 - y) >> 1) : 0; // orphan dy = 0..locnt-1
  int hi0 = (213 - y) >> 1;                    // first orphan dy at high end
  int hicnt = (yi < 20) ? 0 : (21 - hi0);
  int ncnt = locnt + hicnt;
  u16* Xb = X + ((size_t)(b*473 + 32))*HW + (size_t)y*WW;
  int total = ncnt*2016;
  for (int e = threadIdx.x; e < total; e += 256){
    int i = e / 2016, rem = e - i*2016;
    int dy = (i < locnt) ? i : (hi0 + i - locnt);
    int d = rem / 96, xw = rem - d*96;
    *(unsigned int*)(Xb + ((size_t)(dy*21 + d))*HW + 2*xw) = 0u;
  }
}

// ---------------------------------------------------------------------------
// Correlation, round 10: B-row-centric, parity-packed 16x16x32 MFMA, no LDS
// staging (see round 3 notes).
// ---------------------------------------------------------------------------
__global__ __launch_bounds__(256,2) void corr_k(const u16* __restrict__ C2, u16* __restrict__ X){
  __shared__ __align__(16) u16 smE[4160];

  int bid = blockIdx.x;
  int v = (bid & 7)*96 + (bid >> 3);       // XCD-contiguous, bijective (768 = 8*96)
  int b = v / 192, r = v - b*192;

  int tid = threadIdx.x, lane = tid & 63, w = tid >> 6;
  int n = lane & 15, s = lane >> 4;
  int p = w & 1, u0w = (w >> 1)*48;

  const u16* Brow = C2 + ((size_t)(b+4)*HW + (size_t)r*WW)*128;
  const u16* Aimg = C2 + (size_t)b*HW*128;

  uint4 bf[4][5];
  #pragma unroll
  for (int l = 0; l < 5; ++l){
    int zq = u0w + 16*l + n - 16;
    bool vz = ((unsigned)zq < 96u);
    const u16* bp = Brow + (long)(2*zq + p)*128;
    #pragma unroll
    for (int kk = 0; kk < 4; ++kk){
      uint4 t0 = make_uint4(0,0,0,0);
      if (vz) t0 = *(const uint4*)(bp + (kk*4 + s)*8);
      bf[kk][l] = t0;
    }
  }

  int dylo = max(0, (r-170)>>1);
  int dyhi = min(20, (r+20)>>1);

  uint4 A[3][4];
  f32x4 acc[3][3];

  auto loadA = [&](int yy){
    const u16* Ay = Aimg + (size_t)yy*WW*128;
    #pragma unroll
    for (int t = 0; t < 3; ++t){
      const u16* apx = Ay + (size_t)(2*(u0w + 16*t + n) + p)*128;
      #pragma unroll
      for (int kk = 0; kk < 4; ++kk)
        A[t][kk] = *(const uint4*)(apx + (kk*4 + s)*8);
    }
  };

  int nm6 = n - 4*s - 6;
  auto eout = [&](int yy, int dyy){
    #pragma unroll
    for (int t = 0; t < 3; ++t){
      int xb2 = 2*(u0w + 16*t) + p + 8*s;
      #pragma unroll
      for (int j = 0; j < 3; ++j){
        #pragma unroll
        for (int q = 0; q < 4; ++q){
          int dd = nm6 - q + 16*j;
          if ((unsigned)dd <= 20u){
            float val = acc[t][j][q]*(1.f/128.f);
            val = fmaxf(val, 0.f) + 0.1f*fminf(val, 0.f);
            smE[dd*198 + xb2 + 2*q] = f2b(val);
          }
        }
      }
    }
    __syncthreads();
    u16* Xp = X + ((size_t)(b*473 + 32 + dyy*21))*HW + (size_t)yy*WW;
    #pragma unroll
    for (int e0 = 0; e0 < 8; ++e0){
      int e = e0*256 + tid;
      if (e < 2016){
        int d = e/96, xw = e - d*96;
        *(unsigned int*)(Xp + (size_t)d*HW + 2*xw) = *(const unsigned int*)(smE + d*198 + 2*xw);
      }
    }
    __syncthreads();
  };

  loadA(r + 20 - 2*dylo);

  #pragma unroll 1
  for (int dy = dylo; dy <= dyhi; ++dy){
    int y = r + 20 - 2*dy;
    if (dy > dylo) eout(y + 2, dy - 1);
    #pragma unroll
    for (int t = 0; t < 3; ++t)
      #pragma unroll
      for (int j = 0; j < 3; ++j)
        acc[t][j] = (f32x4){0.f, 0.f, 0.f, 0.f};
    #pragma unroll
    for (int kk = 0; kk < 4; ++kk)
      #pragma unroll
      for (int t = 0; t < 3; ++t)
        #pragma unroll
        for (int j = 0; j < 3; ++j)
          acc[t][j] = __builtin_amdgcn_mfma_f32_16x16x32_bf16(
              s8(A[t][kk]), s8(bf[kk][t+j]), acc[t][j], 0, 0, 0);
    if (dy < dyhi) loadA(y - 2);
  }
  eout(r + 20 - 2*dyhi, dyhi);
}

// Final 3x3 conv: contribution-passing, round 12: BRANCHLESS batched loads.
// Round 11's if(ok) guards blocked load batching (VGPR=20, 1.1 TB/s,
// latency-bound). Loads are now always issued (edge rows read adjacent
// workspace regions -- C2 before X, the 364KB gap after X -- both valid
// memory) and out-of-image rows are zeroed post-load with block-uniform
// selects. 24 loads/iter batch in flight; __launch_bounds__(192,2) lifts
// the VGPR cap so RA doesn't squeeze them out.
__global__ __launch_bounds__(192,2) void final_k(const u16* __restrict__ X, const unsigned int* __restrict__ wpb,
                                                 void* __restrict__ out, const int* __restrict__ flag){
  __shared__ float eR[4][2], eL[4][2];
  int x = threadIdx.x, y = blockIdx.x, b = blockIdx.y;
  int w = x >> 6, lane = x & 63;
  const u16* Xb = X + (size_t)b*473*HW;
  float Pm0=0.f,Pm1=0.f,Pl0=0.f,Pl1=0.f,Pr0=0.f,Pr1=0.f;
  bool rok0 = (y > 0), rok2 = (y < HH-1);
  size_t off0 = (size_t)(y-1)*WW + x;
  size_t off1 = (size_t)(y  )*WW + x;
  size_t off2 = (size_t)(y+1)*WW + x;

  #pragma unroll 1
  for (int it = 0; it < 59; ++it){
    int cp0 = it*4;
    unsigned int vv[4][3];
    #pragma unroll
    for (int u = 0; u < 4; ++u){
      size_t base0 = (size_t)(2*(cp0+u))*HW;
      size_t base1 = base0 + HW;
      #pragma unroll
      for (int r = 0; r < 3; ++r){
        size_t off = (r==0) ? off0 : ((r==2) ? off2 : off1);
        unsigned int lo = Xb[base0 + off];
        unsigned int hi = Xb[base1 + off];
        vv[u][r] = lo | (hi << 16);
      }
    }
    if (!rok0){ vv[0][0]=0u; vv[1][0]=0u; vv[2][0]=0u; vv[3][0]=0u; }
    if (!rok2){ vv[0][2]=0u; vv[1][2]=0u; vv[2][2]=0u; vv[3][2]=0u; }
    #pragma unroll
    for (int u = 0; u < 4; ++u){
      const unsigned int* w18 = wpb + (cp0+u)*18;
      #pragma unroll
      for (int r = 0; r < 3; ++r){
        unsigned int v = vv[u][r];
        Pm0 = dot2bf(v, w18[(r*3+1)*2+0], Pm0);
        Pm1 = dot2bf(v, w18[(r*3+1)*2+1], Pm1);
        Pl0 = dot2bf(v, w18[(r*3+2)*2+0], Pl0);
        Pl1 = dot2bf(v, w18[(r*3+2)*2+1], Pl1);
        Pr0 = dot2bf(v, w18[(r*3+0)*2+0], Pr0);
        Pr1 = dot2bf(v, w18[(r*3+0)*2+1], Pr1);
      }
    }
  }
  { // tail pair cp=236 (c0=472, c1 OOB -> weight hi already 0; load lo only)
    const unsigned int* w18 = wpb + 236*18;
    size_t base0 = (size_t)472*HW;
    unsigned int vv[3];
    vv[0] = Xb[base0 + off0];
    vv[1] = Xb[base0 + off1];
    vv[2] = Xb[base0 + off2];
    if (!rok0) vv[0] = 0u;
    if (!rok2) vv[2] = 0u;
    #pragma unroll
    for (int r = 0; r < 3; ++r){
      unsigned int v = vv[r];
      Pm0 = dot2bf(v, w18[(r*3+1)*2+0], Pm0);
      Pm1 = dot2bf(v, w18[(r*3+1)*2+1], Pm1);
      Pl0 = dot2bf(v, w18[(r*3+2)*2+0], Pl0);
      Pl1 = dot2bf(v, w18[(r*3+2)*2+1], Pl1);
      Pr0 = dot2bf(v, w18[(r*3+0)*2+0], Pr0);
      Pr1 = dot2bf(v, w18[(r*3+0)*2+1], Pr1);
    }
  }

  float r0 = __shfl_up(Pr0,1), r1 = __shfl_up(Pr1,1);
  float l0 = __shfl_down(Pl0,1), l1 = __shfl_down(Pl1,1);
  if (x == 0){ eR[0][0]=0.f; eR[0][1]=0.f; eL[3][0]=0.f; eL[3][1]=0.f; }
  if (lane == 63){ eR[w+1][0]=Pr0; eR[w+1][1]=Pr1; }
  if (lane == 0 && w > 0){ eL[w][0]=Pl0; eL[w][1]=Pl1; }
  __syncthreads();
  if (lane == 0){ r0 = eR[w][0]; r1 = eR[w][1]; }
  if (lane == 63){ l0 = eL[w+1][0]; l1 = eL[w+1][1]; }
  float a0 = Pm0 + r0 + l0;
  float a1 = Pm1 + r1 + l1;

  size_t rem = (size_t)y*WW + x;
  size_t i0 = (size_t)(b*2)*HW + rem;
  size_t i1 = (size_t)(b*2+1)*HW + rem;
  if (*flag){
    ((u16*)out)[i0] = f2b(a0);
    ((u16*)out)[i1] = f2b(a1);
  } else {
    ((float*)out)[i0] = a0;
    ((float*)out)[i1] = a1;
  }
}

// Workspace (bytes):
//   C2 [0, 75497472)           conv2 out NHWC bf16 [8][HW][128]
//   X1 [75497472, 113246208)   cvt out NHWC bf16 [8][HW][64] (dies after conv1)
//   H1 [113246208, 150994944)  conv1 out NHWC bf16 (dies after conv2)
//   X  [75497472, 214958080)   concat NCHW bf16 [4][473][HW] (overlays X1+H1)
//   weights at 215322624 (~260 KB)
extern "C" void kernel_launch(void* const* d_in, const int* in_sizes, int n_in,
                              void* d_out, int out_size, void* d_ws, size_t ws_size,
                              hipStream_t stream){
  char* ws = (char*)d_ws;
  u16* C2 = (u16*)ws;
  u16* X1 = (u16*)(ws + 75497472);
  u16* H1 = (u16*)(ws + 113246208);
  u16* X  = (u16*)(ws + 75497472);
  u16* w1m = (u16*)(ws + 215322624);
  u16* w2m = w1m + 36864;
  float* wrf = (float*)(w2m + 73728);
  unsigned int* wpb = (unsigned int*)(wrf + 4096);
  float* b1f = (float*)(wpb + 4266);
  float* b2f = b1f + 64;
  float* rbf = b2f + 128;
  int* flag  = (int*)(rbf + 32);

  detect_k<<<1,256,0,stream>>>((const unsigned int*)d_in[0], flag);
  cvt_t<<<dim3(576,8),256,0,stream>>>(d_in[0], d_in[1], X1, flag);
  prep_w<<<288,256,0,stream>>>(d_in[2], d_in[4], d_in[6], d_in[8],
                               d_in[3], d_in[5], d_in[7],
                               w1m, w2m, wrf, wpb, b1f, b2f, rbf, flag);
  conv_mfma<1><<<dim3(6,48,8),128,0,stream>>>(X1, w1m, b1f, H1);
  conv_mfma<2><<<dim3(6,48,8),256,0,stream>>>(H1, w2m, b2f, C2);
  redir_k<<<576,256,0,stream>>>(C2, wrf, rbf, X);
  zero_k<<<dim3(40,4),256,0,stream>>>(X);
  corr_k<<<dim3(768),256,0,stream>>>(C2, X);
  final_k<<<dim3(192,4),192,0,stream>>>(X, wpb, d_out, flag);
}